// Round 12
// baseline (1110.025 us; speedup 1.0000x reference)
//
#include <hip/hip_runtime.h>
#include <hip/hip_bf16.h>
#include <math.h>

#define NN 4096
#define EE 65536
#define HID_ 128
#define HDIM 32
#define NCOL 4097
#define EHP 4104  // Eh padded row stride (halfs), 16B-aligned rows

static constexpr float SCALE_ATT = 0.17677669529663687f;   // 1/sqrt(32)
static constexpr float INV_SQRT_D = 0.08838834764831845f;  // 1/sqrt(128)
static constexpr float LOG2E = 1.4426950408889634f;

typedef __attribute__((ext_vector_type(8))) short bf16x8;
typedef __attribute__((ext_vector_type(4))) float f32x4;
typedef _Float16 half4v __attribute__((ext_vector_type(4)));

__device__ __forceinline__ float wred64(float v) {
#pragma unroll
  for (int m = 32; m > 0; m >>= 1) v += __shfl_xor(v, m, 64);
  return v;
}

__device__ __forceinline__ ushort f2b(float f) {
  __hip_bfloat16 h = __float2bfloat16(f);
  union { __hip_bfloat16 h; ushort u; } c;
  c.h = h;
  return c.u;
}

// round-half-up bf16 pack of two floats into one u32 (e0 low, e1 high)
__device__ __forceinline__ unsigned pack2bf(float e0, float e1) {
  return ((__float_as_uint(e1) + 0x8000u) & 0xffff0000u) |
         ((__float_as_uint(e0) + 0x8000u) >> 16);
}

// ---------------- generic [4096,128] @ [128,128] GEMM, pair-batched ---------
// COMBINE: X = attention combine ((Opart[dir]+Opart[2+dir]) / lsum), staged
// directly from the attention partials (x0 = Opart base, lp = lpart).
// LNORM: LayerNorm applied to the staged X tile in LDS (g=lng, b=lnb).
template <bool BIAS, bool RELU, bool RESID, bool BCAST, bool LNORM,
          bool COMBINE>
__global__ __launch_bounds__(256, 2) void gemm128_k(
    const float* __restrict__ x0, const float* __restrict__ x1,
    const float* __restrict__ lp, const float* __restrict__ w,
    const float* __restrict__ bias, const float* __restrict__ lng,
    const float* __restrict__ lnb, const float* __restrict__ res0,
    const float* __restrict__ res1, float* __restrict__ o0,
    float* __restrict__ o1, ushort* __restrict__ ob0,
    ushort* __restrict__ ob1) {
  const int dir = blockIdx.y;
  const float* x = dir ? x1 : x0;
  const float* res = dir ? res1 : res0;
  float* out = dir ? o1 : o0;
  ushort* outb = dir ? ob1 : ob0;
  __shared__ float Xs[32][132];
  __shared__ float Ws[32][128];
  const int tid = threadIdx.x;
  const int rowbase = blockIdx.x * 32;
#pragma unroll
  for (int i = 0; i < 4; ++i) {
    int lin = tid + i * 256;
    int r = lin >> 5, c4 = lin & 31;
    if (COMBINE) {
      int rowg = rowbase + r;
      int hh = c4 >> 3;  // head = (c4*4)/32
      float ls = lp[((size_t)(dir * 4 + hh)) * NN + rowg] +
                 lp[((size_t)((2 + dir) * 4 + hh)) * NN + rowg];
      float inv = 1.f / ls;
      float4 a =
          *(const float4*)&x0[((size_t)dir * NN + rowg) * HID_ + c4 * 4];
      float4 b =
          *(const float4*)&x0[((size_t)(2 + dir) * NN + rowg) * HID_ + c4 * 4];
      *(float4*)&Xs[r][c4 * 4] =
          make_float4((a.x + b.x) * inv, (a.y + b.y) * inv, (a.z + b.z) * inv,
                      (a.w + b.w) * inv);
    } else {
      *(float4*)&Xs[r][c4 * 4] =
          *(const float4*)&x[(size_t)(rowbase + r) * HID_ + c4 * 4];
    }
  }
  if (LNORM) {
    __syncthreads();
    int row = tid >> 3, sub = tid & 7;  // 32 rows x 8 threads (8 lanes/row)
    float vals[16];
    float s = 0.f;
#pragma unroll
    for (int i = 0; i < 16; ++i) {
      vals[i] = Xs[row][sub * 16 + i];
      s += vals[i];
    }
    s += __shfl_xor(s, 1, 64);
    s += __shfl_xor(s, 2, 64);
    s += __shfl_xor(s, 4, 64);
    float mean = s * (1.f / 128.f);
    float v2 = 0.f;
#pragma unroll
    for (int i = 0; i < 16; ++i) {
      float d = vals[i] - mean;
      vals[i] = d;
      v2 += d * d;
    }
    v2 += __shfl_xor(v2, 1, 64);
    v2 += __shfl_xor(v2, 2, 64);
    v2 += __shfl_xor(v2, 4, 64);
    float rs = rsqrtf(v2 * (1.f / 128.f) + 1e-5f);
#pragma unroll
    for (int i = 0; i < 16; ++i)
      Xs[row][sub * 16 + i] =
          vals[i] * rs * lng[sub * 16 + i] + lnb[sub * 16 + i];
  }
  float acc[4][4] = {};
  const int tr = tid >> 5, tc = tid & 31;
  const int r0 = tr * 4, c0 = tc * 4;
  for (int k0 = 0; k0 < 128; k0 += 32) {
    __syncthreads();
#pragma unroll
    for (int i = 0; i < 4; ++i) {
      int lin = tid + i * 256;
      int r = lin >> 5, c4 = lin & 31;
      *(float4*)&Ws[r][c4 * 4] =
          *(const float4*)&w[(size_t)(k0 + r) * HID_ + c4 * 4];
    }
    __syncthreads();
#pragma unroll
    for (int kk = 0; kk < 32; kk += 4) {
      float4 wv0 = *(const float4*)&Ws[kk + 0][c0];
      float4 wv1 = *(const float4*)&Ws[kk + 1][c0];
      float4 wv2 = *(const float4*)&Ws[kk + 2][c0];
      float4 wv3 = *(const float4*)&Ws[kk + 3][c0];
#pragma unroll
      for (int r = 0; r < 4; ++r) {
        float4 xv = *(const float4*)&Xs[r0 + r][k0 + kk];
        acc[r][0] += xv.x * wv0.x + xv.y * wv1.x + xv.z * wv2.x + xv.w * wv3.x;
        acc[r][1] += xv.x * wv0.y + xv.y * wv1.y + xv.z * wv2.y + xv.w * wv3.y;
        acc[r][2] += xv.x * wv0.z + xv.y * wv1.z + xv.z * wv2.z + xv.w * wv3.z;
        acc[r][3] += xv.x * wv0.w + xv.y * wv1.w + xv.z * wv2.w + xv.w * wv3.w;
      }
    }
  }
  float4 bv = make_float4(0.f, 0.f, 0.f, 0.f);
  if (BIAS) bv = *(const float4*)&bias[c0];
#pragma unroll
  for (int r = 0; r < 4; ++r) {
    size_t orow = (size_t)(rowbase + r0 + r) * HID_ + c0;
    float4 ov;
    ov.x = acc[r][0] + bv.x;
    ov.y = acc[r][1] + bv.y;
    ov.z = acc[r][2] + bv.z;
    ov.w = acc[r][3] + bv.w;
    if (RESID) {
      float4 rv = *(const float4*)&res[orow];
      ov.x += rv.x; ov.y += rv.y; ov.z += rv.z; ov.w += rv.w;
    }
    if (RELU) {
      ov.x = fmaxf(ov.x, 0.f); ov.y = fmaxf(ov.y, 0.f);
      ov.z = fmaxf(ov.z, 0.f); ov.w = fmaxf(ov.w, 0.f);
    }
    *(float4*)&out[orow] = ov;
    if (BCAST) {
      *(ushort4*)&outb[orow] =
          make_ushort4(f2b(ov.x), f2b(ov.y), f2b(ov.z), f2b(ov.w));
    }
  }
}

// ---- fused Q/K/V projection: grid (128, 2 graphs, 3 = {Q,K,V}) -------------
__global__ __launch_bounds__(256, 2) void gemm_qkv_k(
    const float* __restrict__ x0, const float* __restrict__ x1,
    const float* __restrict__ wq, const float* __restrict__ wk,
    const float* __restrict__ wv, ushort* __restrict__ QA,
    ushort* __restrict__ QB, ushort* __restrict__ KA, ushort* __restrict__ KB,
    ushort* __restrict__ VA, ushort* __restrict__ VB) {
  const int z = blockIdx.z;
  const float* x = blockIdx.y ? x1 : x0;
  const float* w = (z == 0) ? wq : (z == 1 ? wk : wv);
  ushort* out = (z == 0) ? (blockIdx.y ? QB : QA)
                         : (z == 1 ? (blockIdx.y ? KB : KA)
                                   : (blockIdx.y ? VB : VA));
  const float scale = (z == 0) ? SCALE_ATT * LOG2E : 1.f;
  __shared__ float Xs[32][132];
  __shared__ float Ws[32][128];
  const int tid = threadIdx.x;
  const int rowbase = blockIdx.x * 32;
#pragma unroll
  for (int i = 0; i < 4; ++i) {
    int lin = tid + i * 256;
    int r = lin >> 5, c4 = lin & 31;
    *(float4*)&Xs[r][c4 * 4] =
        *(const float4*)&x[(size_t)(rowbase + r) * HID_ + c4 * 4];
  }
  float acc[4][4] = {};
  const int tr = tid >> 5, tc = tid & 31;
  const int r0 = tr * 4, c0 = tc * 4;
  for (int k0 = 0; k0 < 128; k0 += 32) {
    __syncthreads();
#pragma unroll
    for (int i = 0; i < 4; ++i) {
      int lin = tid + i * 256;
      int r = lin >> 5, c4 = lin & 31;
      *(float4*)&Ws[r][c4 * 4] =
          *(const float4*)&w[(size_t)(k0 + r) * HID_ + c4 * 4];
    }
    __syncthreads();
#pragma unroll
    for (int kk = 0; kk < 32; kk += 4) {
      float4 wv0 = *(const float4*)&Ws[kk + 0][c0];
      float4 wv1 = *(const float4*)&Ws[kk + 1][c0];
      float4 wv2 = *(const float4*)&Ws[kk + 2][c0];
      float4 wv3 = *(const float4*)&Ws[kk + 3][c0];
#pragma unroll
      for (int r = 0; r < 4; ++r) {
        float4 xv = *(const float4*)&Xs[r0 + r][k0 + kk];
        acc[r][0] += xv.x * wv0.x + xv.y * wv1.x + xv.z * wv2.x + xv.w * wv3.x;
        acc[r][1] += xv.x * wv0.y + xv.y * wv1.y + xv.z * wv2.y + xv.w * wv3.y;
        acc[r][2] += xv.x * wv0.z + xv.y * wv1.z + xv.z * wv2.z + xv.w * wv3.z;
        acc[r][3] += xv.x * wv0.w + xv.y * wv1.w + xv.z * wv2.w + xv.w * wv3.w;
      }
    }
  }
  if (z < 2) {
#pragma unroll
    for (int r = 0; r < 4; ++r) {
      ushort4 pk = make_ushort4(
          f2b(acc[r][0] * scale), f2b(acc[r][1] * scale),
          f2b(acc[r][2] * scale), f2b(acc[r][3] * scale));
      *(ushort4*)&out[(size_t)(rowbase + r0 + r) * HID_ + c0] = pk;
    }
  } else {
#pragma unroll
    for (int r = 0; r < 4; ++r)
#pragma unroll
      for (int c = 0; c < 4; ++c)
        out[(size_t)(c0 + c) * NN + rowbase + r0 + r] = f2b(acc[r][c]);
  }
}

// ---------------- GCN graph build ------------------------------------------
__global__ void count_deg_k(const int* __restrict__ eiA,
                            const int* __restrict__ eiB, int* cntA, int* cntB) {
  int e = blockIdx.x * 256 + threadIdx.x;
  const int* ei = blockIdx.y ? eiB : eiA;
  int* cnt = blockIdx.y ? cntB : cntA;
  atomicAdd(&cnt[ei[EE + e]], 1);
}

__global__ __launch_bounds__(1024) void scan_k(const int* cntA, const int* cntB,
                                               int* rpA, int* rpB, float* dinvA,
                                               float* dinvB) {
  const int* cnt = blockIdx.y ? cntB : cntA;
  int* rp = blockIdx.y ? rpB : rpA;
  float* dinv = blockIdx.y ? dinvB : dinvA;
  __shared__ int part[1024];
  int tid = threadIdx.x;
  int v0 = cnt[tid * 4], v1 = cnt[tid * 4 + 1], v2 = cnt[tid * 4 + 2],
      v3 = cnt[tid * 4 + 3];
  int tot = v0 + v1 + v2 + v3;
  part[tid] = tot;
  __syncthreads();
  int x = tot;
  for (int off = 1; off < 1024; off <<= 1) {
    int y = (tid >= off) ? part[tid - off] : 0;
    __syncthreads();
    x += y;
    part[tid] = x;
    __syncthreads();
  }
  int excl = x - tot;
  rp[tid * 4] = excl;
  rp[tid * 4 + 1] = excl + v0;
  rp[tid * 4 + 2] = excl + v0 + v1;
  rp[tid * 4 + 3] = excl + v0 + v1 + v2;
  if (tid == 1023) rp[4096] = x;
  dinv[tid * 4] = rsqrtf((float)(v0 + 1));
  dinv[tid * 4 + 1] = rsqrtf((float)(v1 + 1));
  dinv[tid * 4 + 2] = rsqrtf((float)(v2 + 1));
  dinv[tid * 4 + 3] = rsqrtf((float)(v3 + 1));
}

__global__ void fill_k(const int* __restrict__ eiA, const int* __restrict__ eiB,
                       const int* rpA, const int* rpB, int* fillA, int* fillB,
                       int* srcA, int* srcB) {
  int e = blockIdx.x * 256 + threadIdx.x;
  const int* ei = blockIdx.y ? eiB : eiA;
  const int* rp = blockIdx.y ? rpB : rpA;
  int* fill = blockIdx.y ? fillB : fillA;
  int* src = blockIdx.y ? srcB : srcA;
  int d = ei[EE + e], s = ei[e];
  int pos = atomicAdd(&fill[d], 1);
  src[rp[d] + pos] = s;
}

// wave-per-node aggregation + bias + LayerNorm + ReLU
__global__ __launch_bounds__(256) void gcn_agg_k(
    const float* __restrict__ xlA, const float* __restrict__ xlB,
    const int* __restrict__ rpA, const int* __restrict__ rpB,
    const int* __restrict__ srcA, const int* __restrict__ srcB,
    const float* __restrict__ dinvA, const float* __restrict__ dinvB,
    const float* __restrict__ gb, const float* __restrict__ lg,
    const float* __restrict__ lb, float* __restrict__ outA,
    float* __restrict__ outB) {
  const float* xl = blockIdx.y ? xlB : xlA;
  const int* rp = blockIdx.y ? rpB : rpA;
  const int* src = blockIdx.y ? srcB : srcA;
  const float* dinv = blockIdx.y ? dinvB : dinvA;
  float* out = blockIdx.y ? outB : outA;
  int wid = threadIdx.x >> 6, lane = threadIdx.x & 63;
  int node = blockIdx.x * 4 + wid;
  int b = rp[node], e = rp[node + 1];
  float di = dinv[node];
  float a0 = 0.f, a1 = 0.f;
  for (int base = b; base < e; base += 64) {
    int rem = e - base;
    int sv = 0;
    float wv = 0.f;
    if (lane < rem) {
      int s = src[base + lane];
      sv = s;
      wv = dinv[s] * di;
    }
    int nch = rem < 64 ? rem : 64;
    for (int j = 0; j < nch; ++j) {
      int s = __shfl(sv, j, 64);
      float w = __shfl(wv, j, 64);
      a0 += xl[(size_t)s * HID_ + lane] * w;
      a1 += xl[(size_t)s * HID_ + 64 + lane] * w;
    }
  }
  a0 += xl[(size_t)node * HID_ + lane] * di * di;
  a1 += xl[(size_t)node * HID_ + 64 + lane] * di * di;
  a0 += gb[lane];
  a1 += gb[64 + lane];
  float mean = wred64(a0 + a1) * (1.f / 128.f);
  float d0 = a0 - mean, d1 = a1 - mean;
  float var = wred64(d0 * d0 + d1 * d1) * (1.f / 128.f);
  float rs = rsqrtf(var + 1e-5f);
  float o0 = d0 * rs * lg[lane] + lb[lane];
  float o1 = d1 * rs * lg[64 + lane] + lb[64 + lane];
  out[(size_t)node * HID_ + lane] = fmaxf(o0, 0.f);
  out[(size_t)node * HID_ + 64 + lane] = fmaxf(o1, 0.f);
}

// ---------------- MFMA attention, kv-split x2, double-buffered LDS ----------
__global__ __launch_bounds__(256, 4) void attn_mfma_k(
    const ushort* __restrict__ QA, const ushort* __restrict__ KA,
    const ushort* __restrict__ VtA, const ushort* __restrict__ QB,
    const ushort* __restrict__ KB, const ushort* __restrict__ VtB,
    float* __restrict__ Opart, float* __restrict__ lpart) {
  const int qt = blockIdx.x, h = blockIdx.y;
  const int dir = blockIdx.z >> 1, sl = blockIdx.z & 1;
  const ushort* Q = dir ? QB : QA;
  const ushort* K = dir ? KA : KB;
  const ushort* Vt = dir ? VtA : VtB;

  __shared__ ushort KF[2][2048];
  __shared__ ushort VF[2][2048];
  __shared__ ushort PF[4][1024];

  const int tid = threadIdx.x;
  const int w = tid >> 6, l = tid & 63;
  const int lr = l & 15, lg = l >> 4;

  const int qrow = qt * 64 + w * 16 + lr;
  bf16x8 qf = *(const bf16x8*)&Q[(size_t)qrow * HID_ + h * HDIM + lg * 8];

  f32x4 oacc0 = {0.f, 0.f, 0.f, 0.f};
  f32x4 oacc1 = {0.f, 0.f, 0.f, 0.f};
  float lsum = 0.f;

  const int ldst = ((w * 4 + lg) * 16 + lr) * 8;
  const ushort* Kg =
      K + (size_t)(sl * 2048 + w * 16 + lr) * HID_ + h * HDIM + lg * 8;
  const ushort* Vg = Vt + (size_t)(h * HDIM + (w >> 1) * 16 + lr) * NN +
                     sl * 2048 + (w & 1) * 32 + lg * 8;

  {
    bf16x8 k0 = *(const bf16x8*)Kg;
    bf16x8 v0 = *(const bf16x8*)Vg;
    *(bf16x8*)&KF[0][ldst] = k0;
    *(bf16x8*)&VF[0][ldst] = v0;
  }
  __syncthreads();

  for (int t = 0; t < 32; ++t) {
    const int cur = t & 1;
    bf16x8 kreg, vreg;
    if (t < 31) {
      kreg = *(const bf16x8*)&Kg[(size_t)(t + 1) * 64 * HID_];
      vreg = *(const bf16x8*)&Vg[(t + 1) * 64];
    }
#pragma unroll
    for (int s = 0; s < 4; ++s) {
      bf16x8 kf = *(const bf16x8*)&KF[cur][((s * 4 + lg) * 16 + lr) * 8];
      f32x4 c = {0.f, 0.f, 0.f, 0.f};
      c = __builtin_amdgcn_mfma_f32_16x16x32_bf16(kf, qf, c, 0, 0, 0);
      float e0 = exp2f(c[0]), e1 = exp2f(c[1]);
      float e2 = exp2f(c[2]), e3 = exp2f(c[3]);
      lsum += (e0 + e1) + (e2 + e3);
      const int k0 = s >> 1;
      const int lgr = (s & 1) * 2 + (lg >> 1);
      const int e8 = (lg & 1) * 4;
      *(uint2*)&PF[w][((k0 * 4 + lgr) * 16 + lr) * 8 + e8] =
          make_uint2(pack2bf(e0, e1), pack2bf(e2, e3));
    }
#pragma unroll
    for (int k0 = 0; k0 < 2; ++k0) {
      bf16x8 pa = *(const bf16x8*)&PF[w][((k0 * 4 + lg) * 16 + lr) * 8];
      bf16x8 vb0 = *(const bf16x8*)&VF[cur][((k0 * 4 + lg) * 16 + lr) * 8];
      bf16x8 vb1 =
          *(const bf16x8*)&VF[cur][(((2 + k0) * 4 + lg) * 16 + lr) * 8];
      oacc0 = __builtin_amdgcn_mfma_f32_16x16x32_bf16(pa, vb0, oacc0, 0, 0, 0);
      oacc1 = __builtin_amdgcn_mfma_f32_16x16x32_bf16(pa, vb1, oacc1, 0, 0, 0);
    }
    if (t < 31) {
      *(bf16x8*)&KF[cur ^ 1][ldst] = kreg;
      *(bf16x8*)&VF[cur ^ 1][ldst] = vreg;
    }
    __syncthreads();
  }
  lsum += __shfl_xor(lsum, 16, 64);
  lsum += __shfl_xor(lsum, 32, 64);
  const int pb = sl * 2 + dir;
  if (lg == 0)
    lpart[(size_t)(pb * 4 + h) * NN + qt * 64 + w * 16 + lr] = lsum;
#pragma unroll
  for (int r = 0; r < 4; ++r) {
    int q = qt * 64 + w * 16 + lg * 4 + r;
    Opart[((size_t)pb * NN + q) * HID_ + h * HDIM + lr] = oacc0[r];
    Opart[((size_t)pb * NN + q) * HID_ + h * HDIM + 16 + lr] = oacc1[r];
  }
}

// ---------------- logits via bf16 MFMA + fused Eh=exp(L) epilogue -----------
__global__ __launch_bounds__(256, 2) void gemm_nt_mfma_k(
    const ushort* __restrict__ Apb, const ushort* __restrict__ Bpb,
    float* __restrict__ L, _Float16* __restrict__ Eh) {
  __shared__ ushort As[128 * 128];
  __shared__ ushort Bs[128 * 128];
  const int tid = threadIdx.x;
  const int ab = blockIdx.y * 128, bb = blockIdx.x * 128;
#pragma unroll
  for (int i = 0; i < 8; ++i) {
    int lin = tid + i * 256;
    int row = lin >> 4, ch = lin & 15;
    int pch = ch ^ (row & 15);
    *(bf16x8*)&As[row * 128 + pch * 8] =
        *(const bf16x8*)&Apb[(size_t)(ab + row) * HID_ + ch * 8];
    *(bf16x8*)&Bs[row * 128 + pch * 8] =
        *(const bf16x8*)&Bpb[(size_t)(bb + row) * HID_ + ch * 8];
  }
  __syncthreads();
  const int w = tid >> 6, l = tid & 63, lr = l & 15, lg = l >> 4;
  f32x4 acc[2][8];
#pragma unroll
  for (int fm = 0; fm < 2; ++fm)
#pragma unroll
    for (int nf = 0; nf < 8; ++nf) acc[fm][nf] = {0.f, 0.f, 0.f, 0.f};
#pragma unroll
  for (int kc = 0; kc < 4; ++kc) {
    bf16x8 a0 = *(const bf16x8*)
        &As[((w * 2 + 0) * 16 + lr) * 128 + ((kc * 4 + lg) ^ lr) * 8];
    bf16x8 a1 = *(const bf16x8*)
        &As[((w * 2 + 1) * 16 + lr) * 128 + ((kc * 4 + lg) ^ lr) * 8];
#pragma unroll
    for (int nf = 0; nf < 8; ++nf) {
      bf16x8 bf = *(const bf16x8*)
          &Bs[(nf * 16 + lr) * 128 + ((kc * 4 + lg) ^ lr) * 8];
      acc[0][nf] = __builtin_amdgcn_mfma_f32_16x16x32_bf16(a0, bf, acc[0][nf], 0, 0, 0);
      acc[1][nf] = __builtin_amdgcn_mfma_f32_16x16x32_bf16(a1, bf, acc[1][nf], 0, 0, 0);
    }
  }
#pragma unroll
  for (int fm = 0; fm < 2; ++fm)
#pragma unroll
    for (int nf = 0; nf < 8; ++nf)
#pragma unroll
      for (int r = 0; r < 4; ++r) {
        int row = ab + (w * 2 + fm) * 16 + lg * 4 + r;
        int col = bb + nf * 16 + lr;
        float v = acc[fm][nf][r] * INV_SQRT_D;
        L[(size_t)row * NCOL + col] = v;
        Eh[(size_t)row * EHP + col] = (_Float16)exp2f(v * LOG2E);
      }
}

__global__ void null_col_k(const float* __restrict__ Ap,
                           const float* __restrict__ nv, float* __restrict__ L,
                           _Float16* __restrict__ Eh) {
  int row = blockIdx.x, lane = threadIdx.x;
  float s = Ap[(size_t)row * HID_ + lane] * nv[lane] +
            Ap[(size_t)row * HID_ + 64 + lane] * nv[64 + lane];
  s = wred64(s);
  if (lane == 0) {
    float v = s * INV_SQRT_D;
    L[(size_t)row * NCOL + 4096] = v;
    Eh[(size_t)row * EHP + 4096] = (_Float16)exp2f(v * LOG2E);
  }
  if (lane >= 1 && lane < 8) Eh[(size_t)row * EHP + 4096 + lane] = (_Float16)0.f;
}

// ---------------- Sinkhorn: fused row pass + fp16 col partials --------------
// 256 blocks x 16 rows. Phase 1: u_i = 1/(E v) (vinv in LDS, conflict-free
// float4 ownership). Phase 2: per-block fp16 column partials (plain stores).
// Blocks 0..16 also zero t_new for the reduce that follows.
__global__ __launch_bounds__(256) void sink_fused_k(
    const _Float16* __restrict__ Eh, const float* __restrict__ t_old,
    float* __restrict__ t_new, _Float16* __restrict__ colpart,
    float* __restrict__ u, int first) {
  __shared__ float vinv[EHP];
  __shared__ float uls[16];
  const int tid = threadIdx.x, bid = blockIdx.x;
  if (bid < 17) {
    int z = bid * 256 + tid;
    if (z < EHP) t_new[z] = 0.f;
  }
  for (int i = tid; i < EHP; i += 256)
    vinv[i] = (i < NCOL) ? (first ? 1.f : 1.f / t_old[i]) : 0.f;
  __syncthreads();
  const int w = tid >> 6, l = tid & 63;
  const int row0 = bid * 16;
#pragma unroll
  for (int rr = 0; rr < 4; ++rr) {
    int row = row0 + w * 4 + rr;
    const _Float16* Ep = Eh + (size_t)row * EHP;
    float s = 0.f;
    for (int j = l * 4; j < EHP; j += 256) {
      half4v e = *(const half4v*)&Ep[j];
      float4 vv = *(const float4*)&vinv[j];
      s += (float)e[0] * vv.x + (float)e[1] * vv.y + (float)e[2] * vv.z +
           (float)e[3] * vv.w;
    }
    s = wred64(s);
    if (l == 0) {
      float uv = 1.f / s;
      uls[w * 4 + rr] = uv;
      u[row] = uv;
    }
  }
  __syncthreads();
  float ur[16];
#pragma unroll
  for (int r = 0; r < 16; ++r) ur[r] = uls[r];
  _Float16* cp = colpart + (size_t)bid * EHP;
  for (int j = tid * 4; j < EHP; j += 1024) {
    float a0 = 0.f, a1 = 0.f, a2 = 0.f, a3 = 0.f;
#pragma unroll
    for (int r = 0; r < 16; ++r) {
      half4v e = *(const half4v*)&Eh[(size_t)(row0 + r) * EHP + j];
      a0 += (float)e[0] * ur[r];
      a1 += (float)e[1] * ur[r];
      a2 += (float)e[2] * ur[r];
      a3 += (float)e[3] * ur[r];
    }
    half4v pk;
    pk[0] = (_Float16)a0; pk[1] = (_Float16)a1;
    pk[2] = (_Float16)a2; pk[3] = (_Float16)a3;
    *(half4v*)&cp[j] = pk;
  }
}

// reduce 256 partials -> t_new. grid (17, 8): 32 partials per block,
// one atomicAdd per col (8 contenders; t_new pre-zeroed by sink_fused_k).
__global__ __launch_bounds__(256) void sink_reduce_k(
    const _Float16* __restrict__ colpart, float* __restrict__ t_new) {
  int j = blockIdx.x * 256 + threadIdx.x;
  if (j >= EHP) return;
  int b0 = blockIdx.y * 32;
  float s = 0.f;
#pragma unroll 8
  for (int b = 0; b < 32; ++b)
    s += (float)colpart[(size_t)(b0 + b) * EHP + j];
  atomicAdd(&t_new[j], s);
}

// P = Eh * u_i * (1/t_j)
__global__ __launch_bounds__(256) void sink_finalE_k(
    const _Float16* __restrict__ Eh, const float* __restrict__ u,
    const float* __restrict__ t, float* __restrict__ P) {
  __shared__ float vls[NCOL];
  int tid = threadIdx.x, row = blockIdx.x;
  for (int i = tid; i < NCOL; i += 256) vls[i] = 1.f / t[i];
  __syncthreads();
  float ur = u[row];
  const _Float16* Ep = Eh + (size_t)row * EHP;
  float* Pp = P + (size_t)row * NCOL;
  for (int j = tid; j < NCOL; j += 256) Pp[j] = (float)Ep[j] * ur * vls[j];
}

// ---------------- host ------------------------------------------------------
extern "C" void kernel_launch(void* const* d_in, const int* in_sizes, int n_in,
                              void* d_out, int out_size, void* d_ws,
                              size_t ws_size, hipStream_t stream) {
  const float* A_x = (const float*)d_in[0];
  const int* A_ei = (const int*)d_in[1];
  const float* B_x = (const float*)d_in[2];
  const int* B_ei = (const int*)d_in[3];
  const float* in_w = (const float*)d_in[4];
  const float* in_b = (const float*)d_in[5];
  const float* gcn_w = (const float*)d_in[6];
  const float* gcn_b = (const float*)d_in[7];
  const float* lng = (const float*)d_in[8];
  const float* lnb = (const float*)d_in[9];
  const float* cq = (const float*)d_in[10];
  const float* ck = (const float*)d_in[11];
  const float* cv = (const float*)d_in[12];
  const float* co = (const float*)d_in[13];
  const float* cob = (const float*)d_in[14];
  const float* plg = (const float*)d_in[15];
  const float* plb = (const float*)d_in[16];
  const float* pw = (const float*)d_in[17];
  const float* pb = (const float*)d_in[18];
  const float* nullv = (const float*)d_in[19];
  const float* w1 = (const float*)d_in[20];
  const float* b1 = (const float*)d_in[21];
  const float* w2 = (const float*)d_in[22];
  const float* b2 = (const float*)d_in[23];

  float* ws = (float*)d_ws;
  size_t off = 0;
  auto alloc = [&](size_t n) { float* p = ws + off; off += n; return p; };
  const size_t NHE = (size_t)NN * HID_;
  // --- persistent zone (alive across sinkhorn) ---
  float* tA = alloc(NHE);
  float* tB = alloc(NHE);
  float* Ap = alloc(NHE);
  float* Bp = alloc(NHE);
  ushort* Apb = (ushort*)alloc(NHE / 2);
  ushort* Bpb = (ushort*)alloc(NHE / 2);
  float* uvec = alloc(NN);
  float* t0 = alloc(EHP);
  float* t1 = alloc(EHP);
  // --- overlay zone: encoder/attention buffers, later reused as Eh ---
  float* zone = ws + off;
  float* hA0 = alloc(NHE); float* hB0 = alloc(NHE);
  float* hA1 = alloc(NHE); float* hB1 = alloc(NHE);
  float* QA = alloc(NHE);  float* KAb = alloc(NHE); float* VAb = alloc(NHE);
  float* QB = alloc(NHE);  float* KBb = alloc(NHE); float* VBb = alloc(NHE);
  float* Opart = alloc(4 * NHE);
  float* lpart = alloc((size_t)16 * NN);
  float* dinvA = alloc(NN); float* dinvB = alloc(NN);
  int* ib = (int*)(ws + off);
  int* cntA = ib;             int* cntB = cntA + NN;
  int* fillA = cntB + NN;     int* fillB = fillA + NN;
  int* rpA = fillB + NN;      int* rpB = rpA + (NN + 1);
  int* srcA = rpB + (NN + 1); int* srcB = srcA + EE;
  size_t ints_floats = (size_t)(4 * NN + 2 * (NN + 1) + 2 * EE);
  // Eh overlays the zone; keep off past both the named buffers and Eh
  _Float16* Eh = (_Float16*)zone;
  {
    size_t named = (size_t)((ws + off) - zone) + ints_floats;
    size_t eh_floats = ((size_t)NN * EHP + 1) / 2;
    size_t need = eh_floats > named ? eh_floats : named;
    off = (size_t)(zone - ws) + need;
  }
  // fp16 colpart after the Eh overlay (256 x EHP halfs = 2.1 MB)
  _Float16* colpart = (_Float16*)alloc((size_t)256 * EHP / 2 + 8);

  float* Lout = (float*)d_out;
  float* Pout = Lout + (size_t)NN * NCOL;
  float* zA = Pout + (size_t)NN * NCOL;
  float* zB = zA + NHE;

  hipMemsetAsync(cntA, 0, 4 * NN * sizeof(int), stream);  // cnt + fill

  // input projection
  gemm128_k<true, false, false, false, false, false>
      <<<dim3(128, 2), 256, 0, stream>>>(A_x, B_x, nullptr, in_w, in_b,
                                         nullptr, nullptr, nullptr, nullptr,
                                         hA0, hB0, nullptr, nullptr);
  // CSR build
  count_deg_k<<<dim3(256, 2), 256, 0, stream>>>(A_ei, B_ei, cntA, cntB);
  scan_k<<<dim3(1, 2), 1024, 0, stream>>>(cntA, cntB, rpA, rpB, dinvA, dinvB);
  fill_k<<<dim3(256, 2), 256, 0, stream>>>(A_ei, B_ei, rpA, rpB, fillA, fillB,
                                           srcA, srcB);
  // GCN encode
  float* hA = hA0; float* hB = hB0; float* aA = hA1; float* aB = hB1;
  for (int l = 0; l < 2; ++l) {
    gemm128_k<false, false, false, false, false, false>
        <<<dim3(128, 2), 256, 0, stream>>>(
            hA, hB, nullptr, gcn_w + (size_t)l * HID_ * HID_, nullptr, nullptr,
            nullptr, nullptr, nullptr, tA, tB, nullptr, nullptr);
    gcn_agg_k<<<dim3(1024, 2), 256, 0, stream>>>(
        tA, tB, rpA, rpB, srcA, srcB, dinvA, dinvB, gcn_b + l * HID_,
        lng + l * HID_, lnb + l * HID_, hA, hB);
  }
  // cross attention layers (bf16 MFMA; combine fused into O-projection)
  for (int l = 0; l < 3; ++l) {
    const float* wq = cq + (size_t)l * HID_ * HID_;
    const float* wk = ck + (size_t)l * HID_ * HID_;
    const float* wv = cv + (size_t)l * HID_ * HID_;
    const float* wo = co + (size_t)l * HID_ * HID_;
    gemm_qkv_k<<<dim3(128, 2, 3), 256, 0, stream>>>(
        hA, hB, wq, wk, wv, (ushort*)QA, (ushort*)QB, (ushort*)KAb,
        (ushort*)KBb, (ushort*)VAb, (ushort*)VBb);
    attn_mfma_k<<<dim3(64, 4, 4), 256, 0, stream>>>(
        (ushort*)QA, (ushort*)KAb, (ushort*)VAb, (ushort*)QB, (ushort*)KBb,
        (ushort*)VBb, Opart, lpart);
    // O-projection with inline attention combine + bias + residual
    gemm128_k<true, false, true, false, false, true>
        <<<dim3(128, 2), 256, 0, stream>>>(Opart, nullptr, lpart, wo,
                                           cob + l * HID_, nullptr, nullptr,
                                           hA, hB, aA, aB, nullptr, nullptr);
    float* t;
    t = hA; hA = aA; aA = t;
    t = hB; hB = aB; aB = t;
  }
  // post-LN fused into projection (fp32 out + fused bf16 cast)
  gemm128_k<true, false, false, true, true, false>
      <<<dim3(128, 2), 256, 0, stream>>>(hA, hB, nullptr, pw, pb, plg, plb,
                                         nullptr, nullptr, Ap, Bp, Apb, Bpb);
  // logits + E = exp(L) (fp16), then null column
  gemm_nt_mfma_k<<<dim3(32, 32), 256, 0, stream>>>(Apb, Bpb, Lout, Eh);
  null_col_k<<<NN, 64, 0, stream>>>(Ap, nullv, Lout, Eh);
  // sinkhorn: fused row+colpart (fp16), contention-free reduce; ping-pong t
  float* tb[2] = {t0, t1};
  for (int it = 0; it < 20; ++it) {
    float* told = tb[it & 1];
    float* tnew = tb[(it + 1) & 1];
    sink_fused_k<<<256, 256, 0, stream>>>(Eh, told, tnew, colpart, uvec,
                                          it == 0 ? 1 : 0);
    sink_reduce_k<<<dim3(17, 8), 256, 0, stream>>>(colpart, tnew);
  }
  sink_finalE_k<<<NN, 256, 0, stream>>>(Eh, uvec, tb[0], Pout);
  // correspondence head
  gemm128_k<true, true, false, false, false, false>
      <<<dim3(128, 2), 256, 0, stream>>>(Ap, Bp, nullptr, w1, b1, nullptr,
                                         nullptr, nullptr, nullptr, tA, tB,
                                         nullptr, nullptr);
  gemm128_k<true, false, false, false, false, false>
      <<<dim3(128, 2), 256, 0, stream>>>(tA, tB, nullptr, w2, b2, nullptr,
                                         nullptr, nullptr, nullptr, zA, zB,
                                         nullptr, nullptr);
}

// Round 13
// 970.927 us; speedup vs baseline: 1.1433x; 1.1433x over previous
//
#include <hip/hip_runtime.h>
#include <hip/hip_bf16.h>
#include <math.h>

#define NN 4096
#define EE 65536
#define HID_ 128
#define HDIM 32
#define NCOL 4097
#define EHP 4104  // Eh padded row stride (halfs), 16B-aligned rows

static constexpr float SCALE_ATT = 0.17677669529663687f;   // 1/sqrt(32)
static constexpr float INV_SQRT_D = 0.08838834764831845f;  // 1/sqrt(128)
static constexpr float LOG2E = 1.4426950408889634f;

typedef __attribute__((ext_vector_type(8))) short bf16x8;
typedef __attribute__((ext_vector_type(4))) float f32x4;
typedef _Float16 half4v __attribute__((ext_vector_type(4)));

__device__ __forceinline__ float wred64(float v) {
#pragma unroll
  for (int m = 32; m > 0; m >>= 1) v += __shfl_xor(v, m, 64);
  return v;
}

__device__ __forceinline__ ushort f2b(float f) {
  __hip_bfloat16 h = __float2bfloat16(f);
  union { __hip_bfloat16 h; ushort u; } c;
  c.h = h;
  return c.u;
}

// round-half-up bf16 pack of two floats into one u32 (e0 low, e1 high)
__device__ __forceinline__ unsigned pack2bf(float e0, float e1) {
  return ((__float_as_uint(e1) + 0x8000u) & 0xffff0000u) |
         ((__float_as_uint(e0) + 0x8000u) >> 16);
}

// ---------------- generic [4096,128] @ [128,128] GEMM, pair-batched ---------
// COMBINE: X = attention combine ((Opart[dir]+Opart[2+dir]) / lsum), staged
// directly from the attention partials (x0 = Opart base, lp = lpart).
// LNORM: LayerNorm applied to the staged X tile in LDS (g=lng, b=lnb).
template <bool BIAS, bool RELU, bool RESID, bool BCAST, bool LNORM,
          bool COMBINE>
__global__ __launch_bounds__(256, 2) void gemm128_k(
    const float* __restrict__ x0, const float* __restrict__ x1,
    const float* __restrict__ lp, const float* __restrict__ w,
    const float* __restrict__ bias, const float* __restrict__ lng,
    const float* __restrict__ lnb, const float* __restrict__ res0,
    const float* __restrict__ res1, float* __restrict__ o0,
    float* __restrict__ o1, ushort* __restrict__ ob0,
    ushort* __restrict__ ob1) {
  const int dir = blockIdx.y;
  const float* x = dir ? x1 : x0;
  const float* res = dir ? res1 : res0;
  float* out = dir ? o1 : o0;
  ushort* outb = dir ? ob1 : ob0;
  __shared__ float Xs[32][132];
  __shared__ float Ws[32][128];
  const int tid = threadIdx.x;
  const int rowbase = blockIdx.x * 32;
#pragma unroll
  for (int i = 0; i < 4; ++i) {
    int lin = tid + i * 256;
    int r = lin >> 5, c4 = lin & 31;
    if (COMBINE) {
      int rowg = rowbase + r;
      int hh = c4 >> 3;  // head = (c4*4)/32
      float ls = lp[((size_t)(dir * 4 + hh)) * NN + rowg] +
                 lp[((size_t)((2 + dir) * 4 + hh)) * NN + rowg];
      float inv = 1.f / ls;
      float4 a =
          *(const float4*)&x0[((size_t)dir * NN + rowg) * HID_ + c4 * 4];
      float4 b =
          *(const float4*)&x0[((size_t)(2 + dir) * NN + rowg) * HID_ + c4 * 4];
      *(float4*)&Xs[r][c4 * 4] =
          make_float4((a.x + b.x) * inv, (a.y + b.y) * inv, (a.z + b.z) * inv,
                      (a.w + b.w) * inv);
    } else {
      *(float4*)&Xs[r][c4 * 4] =
          *(const float4*)&x[(size_t)(rowbase + r) * HID_ + c4 * 4];
    }
  }
  if (LNORM) {
    __syncthreads();
    int row = tid >> 3, sub = tid & 7;  // 32 rows x 8 threads (8 lanes/row)
    float vals[16];
    float s = 0.f;
#pragma unroll
    for (int i = 0; i < 16; ++i) {
      vals[i] = Xs[row][sub * 16 + i];
      s += vals[i];
    }
    s += __shfl_xor(s, 1, 64);
    s += __shfl_xor(s, 2, 64);
    s += __shfl_xor(s, 4, 64);
    float mean = s * (1.f / 128.f);
    float v2 = 0.f;
#pragma unroll
    for (int i = 0; i < 16; ++i) {
      float d = vals[i] - mean;
      vals[i] = d;
      v2 += d * d;
    }
    v2 += __shfl_xor(v2, 1, 64);
    v2 += __shfl_xor(v2, 2, 64);
    v2 += __shfl_xor(v2, 4, 64);
    float rs = rsqrtf(v2 * (1.f / 128.f) + 1e-5f);
#pragma unroll
    for (int i = 0; i < 16; ++i)
      Xs[row][sub * 16 + i] =
          vals[i] * rs * lng[sub * 16 + i] + lnb[sub * 16 + i];
  }
  float acc[4][4] = {};
  const int tr = tid >> 5, tc = tid & 31;
  const int r0 = tr * 4, c0 = tc * 4;
  for (int k0 = 0; k0 < 128; k0 += 32) {
    __syncthreads();
#pragma unroll
    for (int i = 0; i < 4; ++i) {
      int lin = tid + i * 256;
      int r = lin >> 5, c4 = lin & 31;
      *(float4*)&Ws[r][c4 * 4] =
          *(const float4*)&w[(size_t)(k0 + r) * HID_ + c4 * 4];
    }
    __syncthreads();
#pragma unroll
    for (int kk = 0; kk < 32; kk += 4) {
      float4 wv0 = *(const float4*)&Ws[kk + 0][c0];
      float4 wv1 = *(const float4*)&Ws[kk + 1][c0];
      float4 wv2 = *(const float4*)&Ws[kk + 2][c0];
      float4 wv3 = *(const float4*)&Ws[kk + 3][c0];
#pragma unroll
      for (int r = 0; r < 4; ++r) {
        float4 xv = *(const float4*)&Xs[r0 + r][k0 + kk];
        acc[r][0] += xv.x * wv0.x + xv.y * wv1.x + xv.z * wv2.x + xv.w * wv3.x;
        acc[r][1] += xv.x * wv0.y + xv.y * wv1.y + xv.z * wv2.y + xv.w * wv3.y;
        acc[r][2] += xv.x * wv0.z + xv.y * wv1.z + xv.z * wv2.z + xv.w * wv3.z;
        acc[r][3] += xv.x * wv0.w + xv.y * wv1.w + xv.z * wv2.w + xv.w * wv3.w;
      }
    }
  }
  float4 bv = make_float4(0.f, 0.f, 0.f, 0.f);
  if (BIAS) bv = *(const float4*)&bias[c0];
#pragma unroll
  for (int r = 0; r < 4; ++r) {
    size_t orow = (size_t)(rowbase + r0 + r) * HID_ + c0;
    float4 ov;
    ov.x = acc[r][0] + bv.x;
    ov.y = acc[r][1] + bv.y;
    ov.z = acc[r][2] + bv.z;
    ov.w = acc[r][3] + bv.w;
    if (RESID) {
      float4 rv = *(const float4*)&res[orow];
      ov.x += rv.x; ov.y += rv.y; ov.z += rv.z; ov.w += rv.w;
    }
    if (RELU) {
      ov.x = fmaxf(ov.x, 0.f); ov.y = fmaxf(ov.y, 0.f);
      ov.z = fmaxf(ov.z, 0.f); ov.w = fmaxf(ov.w, 0.f);
    }
    *(float4*)&out[orow] = ov;
    if (BCAST) {
      *(ushort4*)&outb[orow] =
          make_ushort4(f2b(ov.x), f2b(ov.y), f2b(ov.z), f2b(ov.w));
    }
  }
}

// ---- fused Q/K/V projection: grid (128, 2 graphs, 3 = {Q,K,V}) -------------
__global__ __launch_bounds__(256, 2) void gemm_qkv_k(
    const float* __restrict__ x0, const float* __restrict__ x1,
    const float* __restrict__ wq, const float* __restrict__ wk,
    const float* __restrict__ wv, ushort* __restrict__ QA,
    ushort* __restrict__ QB, ushort* __restrict__ KA, ushort* __restrict__ KB,
    ushort* __restrict__ VA, ushort* __restrict__ VB) {
  const int z = blockIdx.z;
  const float* x = blockIdx.y ? x1 : x0;
  const float* w = (z == 0) ? wq : (z == 1 ? wk : wv);
  ushort* out = (z == 0) ? (blockIdx.y ? QB : QA)
                         : (z == 1 ? (blockIdx.y ? KB : KA)
                                   : (blockIdx.y ? VB : VA));
  const float scale = (z == 0) ? SCALE_ATT * LOG2E : 1.f;
  __shared__ float Xs[32][132];
  __shared__ float Ws[32][128];
  const int tid = threadIdx.x;
  const int rowbase = blockIdx.x * 32;
#pragma unroll
  for (int i = 0; i < 4; ++i) {
    int lin = tid + i * 256;
    int r = lin >> 5, c4 = lin & 31;
    *(float4*)&Xs[r][c4 * 4] =
        *(const float4*)&x[(size_t)(rowbase + r) * HID_ + c4 * 4];
  }
  float acc[4][4] = {};
  const int tr = tid >> 5, tc = tid & 31;
  const int r0 = tr * 4, c0 = tc * 4;
  for (int k0 = 0; k0 < 128; k0 += 32) {
    __syncthreads();
#pragma unroll
    for (int i = 0; i < 4; ++i) {
      int lin = tid + i * 256;
      int r = lin >> 5, c4 = lin & 31;
      *(float4*)&Ws[r][c4 * 4] =
          *(const float4*)&w[(size_t)(k0 + r) * HID_ + c4 * 4];
    }
    __syncthreads();
#pragma unroll
    for (int kk = 0; kk < 32; kk += 4) {
      float4 wv0 = *(const float4*)&Ws[kk + 0][c0];
      float4 wv1 = *(const float4*)&Ws[kk + 1][c0];
      float4 wv2 = *(const float4*)&Ws[kk + 2][c0];
      float4 wv3 = *(const float4*)&Ws[kk + 3][c0];
#pragma unroll
      for (int r = 0; r < 4; ++r) {
        float4 xv = *(const float4*)&Xs[r0 + r][k0 + kk];
        acc[r][0] += xv.x * wv0.x + xv.y * wv1.x + xv.z * wv2.x + xv.w * wv3.x;
        acc[r][1] += xv.x * wv0.y + xv.y * wv1.y + xv.z * wv2.y + xv.w * wv3.y;
        acc[r][2] += xv.x * wv0.z + xv.y * wv1.z + xv.z * wv2.z + xv.w * wv3.z;
        acc[r][3] += xv.x * wv0.w + xv.y * wv1.w + xv.z * wv2.w + xv.w * wv3.w;
      }
    }
  }
  if (z < 2) {
#pragma unroll
    for (int r = 0; r < 4; ++r) {
      ushort4 pk = make_ushort4(
          f2b(acc[r][0] * scale), f2b(acc[r][1] * scale),
          f2b(acc[r][2] * scale), f2b(acc[r][3] * scale));
      *(ushort4*)&out[(size_t)(rowbase + r0 + r) * HID_ + c0] = pk;
    }
  } else {
#pragma unroll
    for (int r = 0; r < 4; ++r)
#pragma unroll
      for (int c = 0; c < 4; ++c)
        out[(size_t)(c0 + c) * NN + rowbase + r0 + r] = f2b(acc[r][c]);
  }
}

// ---------------- GCN graph build ------------------------------------------
__global__ void count_deg_k(const int* __restrict__ eiA,
                            const int* __restrict__ eiB, int* cntA, int* cntB) {
  int e = blockIdx.x * 256 + threadIdx.x;
  const int* ei = blockIdx.y ? eiB : eiA;
  int* cnt = blockIdx.y ? cntB : cntA;
  atomicAdd(&cnt[ei[EE + e]], 1);
}

__global__ __launch_bounds__(1024) void scan_k(const int* cntA, const int* cntB,
                                               int* rpA, int* rpB, float* dinvA,
                                               float* dinvB) {
  const int* cnt = blockIdx.y ? cntB : cntA;
  int* rp = blockIdx.y ? rpB : rpA;
  float* dinv = blockIdx.y ? dinvB : dinvA;
  __shared__ int part[1024];
  int tid = threadIdx.x;
  int v0 = cnt[tid * 4], v1 = cnt[tid * 4 + 1], v2 = cnt[tid * 4 + 2],
      v3 = cnt[tid * 4 + 3];
  int tot = v0 + v1 + v2 + v3;
  part[tid] = tot;
  __syncthreads();
  int x = tot;
  for (int off = 1; off < 1024; off <<= 1) {
    int y = (tid >= off) ? part[tid - off] : 0;
    __syncthreads();
    x += y;
    part[tid] = x;
    __syncthreads();
  }
  int excl = x - tot;
  rp[tid * 4] = excl;
  rp[tid * 4 + 1] = excl + v0;
  rp[tid * 4 + 2] = excl + v0 + v1;
  rp[tid * 4 + 3] = excl + v0 + v1 + v2;
  if (tid == 1023) rp[4096] = x;
  dinv[tid * 4] = rsqrtf((float)(v0 + 1));
  dinv[tid * 4 + 1] = rsqrtf((float)(v1 + 1));
  dinv[tid * 4 + 2] = rsqrtf((float)(v2 + 1));
  dinv[tid * 4 + 3] = rsqrtf((float)(v3 + 1));
}

__global__ void fill_k(const int* __restrict__ eiA, const int* __restrict__ eiB,
                       const int* rpA, const int* rpB, int* fillA, int* fillB,
                       int* srcA, int* srcB) {
  int e = blockIdx.x * 256 + threadIdx.x;
  const int* ei = blockIdx.y ? eiB : eiA;
  const int* rp = blockIdx.y ? rpB : rpA;
  int* fill = blockIdx.y ? fillB : fillA;
  int* src = blockIdx.y ? srcB : srcA;
  int d = ei[EE + e], s = ei[e];
  int pos = atomicAdd(&fill[d], 1);
  src[rp[d] + pos] = s;
}

// wave-per-node aggregation + bias + LayerNorm + ReLU
__global__ __launch_bounds__(256) void gcn_agg_k(
    const float* __restrict__ xlA, const float* __restrict__ xlB,
    const int* __restrict__ rpA, const int* __restrict__ rpB,
    const int* __restrict__ srcA, const int* __restrict__ srcB,
    const float* __restrict__ dinvA, const float* __restrict__ dinvB,
    const float* __restrict__ gb, const float* __restrict__ lg,
    const float* __restrict__ lb, float* __restrict__ outA,
    float* __restrict__ outB) {
  const float* xl = blockIdx.y ? xlB : xlA;
  const int* rp = blockIdx.y ? rpB : rpA;
  const int* src = blockIdx.y ? srcB : srcA;
  const float* dinv = blockIdx.y ? dinvB : dinvA;
  float* out = blockIdx.y ? outB : outA;
  int wid = threadIdx.x >> 6, lane = threadIdx.x & 63;
  int node = blockIdx.x * 4 + wid;
  int b = rp[node], e = rp[node + 1];
  float di = dinv[node];
  float a0 = 0.f, a1 = 0.f;
  for (int base = b; base < e; base += 64) {
    int rem = e - base;
    int sv = 0;
    float wv = 0.f;
    if (lane < rem) {
      int s = src[base + lane];
      sv = s;
      wv = dinv[s] * di;
    }
    int nch = rem < 64 ? rem : 64;
    for (int j = 0; j < nch; ++j) {
      int s = __shfl(sv, j, 64);
      float w = __shfl(wv, j, 64);
      a0 += xl[(size_t)s * HID_ + lane] * w;
      a1 += xl[(size_t)s * HID_ + 64 + lane] * w;
    }
  }
  a0 += xl[(size_t)node * HID_ + lane] * di * di;
  a1 += xl[(size_t)node * HID_ + 64 + lane] * di * di;
  a0 += gb[lane];
  a1 += gb[64 + lane];
  float mean = wred64(a0 + a1) * (1.f / 128.f);
  float d0 = a0 - mean, d1 = a1 - mean;
  float var = wred64(d0 * d0 + d1 * d1) * (1.f / 128.f);
  float rs = rsqrtf(var + 1e-5f);
  float o0 = d0 * rs * lg[lane] + lb[lane];
  float o1 = d1 * rs * lg[64 + lane] + lb[64 + lane];
  out[(size_t)node * HID_ + lane] = fmaxf(o0, 0.f);
  out[(size_t)node * HID_ + 64 + lane] = fmaxf(o1, 0.f);
}

// ---------------- MFMA attention, kv-split x2, double-buffered LDS ----------
__global__ __launch_bounds__(256, 4) void attn_mfma_k(
    const ushort* __restrict__ QA, const ushort* __restrict__ KA,
    const ushort* __restrict__ VtA, const ushort* __restrict__ QB,
    const ushort* __restrict__ KB, const ushort* __restrict__ VtB,
    float* __restrict__ Opart, float* __restrict__ lpart) {
  const int qt = blockIdx.x, h = blockIdx.y;
  const int dir = blockIdx.z >> 1, sl = blockIdx.z & 1;
  const ushort* Q = dir ? QB : QA;
  const ushort* K = dir ? KA : KB;
  const ushort* Vt = dir ? VtA : VtB;

  __shared__ ushort KF[2][2048];
  __shared__ ushort VF[2][2048];
  __shared__ ushort PF[4][1024];

  const int tid = threadIdx.x;
  const int w = tid >> 6, l = tid & 63;
  const int lr = l & 15, lg = l >> 4;

  const int qrow = qt * 64 + w * 16 + lr;
  bf16x8 qf = *(const bf16x8*)&Q[(size_t)qrow * HID_ + h * HDIM + lg * 8];

  f32x4 oacc0 = {0.f, 0.f, 0.f, 0.f};
  f32x4 oacc1 = {0.f, 0.f, 0.f, 0.f};
  float lsum = 0.f;

  const int ldst = ((w * 4 + lg) * 16 + lr) * 8;
  const ushort* Kg =
      K + (size_t)(sl * 2048 + w * 16 + lr) * HID_ + h * HDIM + lg * 8;
  const ushort* Vg = Vt + (size_t)(h * HDIM + (w >> 1) * 16 + lr) * NN +
                     sl * 2048 + (w & 1) * 32 + lg * 8;

  {
    bf16x8 k0 = *(const bf16x8*)Kg;
    bf16x8 v0 = *(const bf16x8*)Vg;
    *(bf16x8*)&KF[0][ldst] = k0;
    *(bf16x8*)&VF[0][ldst] = v0;
  }
  __syncthreads();

  for (int t = 0; t < 32; ++t) {
    const int cur = t & 1;
    bf16x8 kreg, vreg;
    if (t < 31) {
      kreg = *(const bf16x8*)&Kg[(size_t)(t + 1) * 64 * HID_];
      vreg = *(const bf16x8*)&Vg[(t + 1) * 64];
    }
#pragma unroll
    for (int s = 0; s < 4; ++s) {
      bf16x8 kf = *(const bf16x8*)&KF[cur][((s * 4 + lg) * 16 + lr) * 8];
      f32x4 c = {0.f, 0.f, 0.f, 0.f};
      c = __builtin_amdgcn_mfma_f32_16x16x32_bf16(kf, qf, c, 0, 0, 0);
      float e0 = exp2f(c[0]), e1 = exp2f(c[1]);
      float e2 = exp2f(c[2]), e3 = exp2f(c[3]);
      lsum += (e0 + e1) + (e2 + e3);
      const int k0 = s >> 1;
      const int lgr = (s & 1) * 2 + (lg >> 1);
      const int e8 = (lg & 1) * 4;
      *(uint2*)&PF[w][((k0 * 4 + lgr) * 16 + lr) * 8 + e8] =
          make_uint2(pack2bf(e0, e1), pack2bf(e2, e3));
    }
#pragma unroll
    for (int k0 = 0; k0 < 2; ++k0) {
      bf16x8 pa = *(const bf16x8*)&PF[w][((k0 * 4 + lg) * 16 + lr) * 8];
      bf16x8 vb0 = *(const bf16x8*)&VF[cur][((k0 * 4 + lg) * 16 + lr) * 8];
      bf16x8 vb1 =
          *(const bf16x8*)&VF[cur][(((2 + k0) * 4 + lg) * 16 + lr) * 8];
      oacc0 = __builtin_amdgcn_mfma_f32_16x16x32_bf16(pa, vb0, oacc0, 0, 0, 0);
      oacc1 = __builtin_amdgcn_mfma_f32_16x16x32_bf16(pa, vb1, oacc1, 0, 0, 0);
    }
    if (t < 31) {
      *(bf16x8*)&KF[cur ^ 1][ldst] = kreg;
      *(bf16x8*)&VF[cur ^ 1][ldst] = vreg;
    }
    __syncthreads();
  }
  lsum += __shfl_xor(lsum, 16, 64);
  lsum += __shfl_xor(lsum, 32, 64);
  const int pb = sl * 2 + dir;
  if (lg == 0)
    lpart[(size_t)(pb * 4 + h) * NN + qt * 64 + w * 16 + lr] = lsum;
#pragma unroll
  for (int r = 0; r < 4; ++r) {
    int q = qt * 64 + w * 16 + lg * 4 + r;
    Opart[((size_t)pb * NN + q) * HID_ + h * HDIM + lr] = oacc0[r];
    Opart[((size_t)pb * NN + q) * HID_ + h * HDIM + 16 + lr] = oacc1[r];
  }
}

// ---------------- logits via bf16 MFMA + fused Eh=exp(L) epilogue -----------
__global__ __launch_bounds__(256, 2) void gemm_nt_mfma_k(
    const ushort* __restrict__ Apb, const ushort* __restrict__ Bpb,
    float* __restrict__ L, _Float16* __restrict__ Eh) {
  __shared__ ushort As[128 * 128];
  __shared__ ushort Bs[128 * 128];
  const int tid = threadIdx.x;
  const int ab = blockIdx.y * 128, bb = blockIdx.x * 128;
#pragma unroll
  for (int i = 0; i < 8; ++i) {
    int lin = tid + i * 256;
    int row = lin >> 4, ch = lin & 15;
    int pch = ch ^ (row & 15);
    *(bf16x8*)&As[row * 128 + pch * 8] =
        *(const bf16x8*)&Apb[(size_t)(ab + row) * HID_ + ch * 8];
    *(bf16x8*)&Bs[row * 128 + pch * 8] =
        *(const bf16x8*)&Bpb[(size_t)(bb + row) * HID_ + ch * 8];
  }
  __syncthreads();
  const int w = tid >> 6, l = tid & 63, lr = l & 15, lg = l >> 4;
  f32x4 acc[2][8];
#pragma unroll
  for (int fm = 0; fm < 2; ++fm)
#pragma unroll
    for (int nf = 0; nf < 8; ++nf) acc[fm][nf] = {0.f, 0.f, 0.f, 0.f};
#pragma unroll
  for (int kc = 0; kc < 4; ++kc) {
    bf16x8 a0 = *(const bf16x8*)
        &As[((w * 2 + 0) * 16 + lr) * 128 + ((kc * 4 + lg) ^ lr) * 8];
    bf16x8 a1 = *(const bf16x8*)
        &As[((w * 2 + 1) * 16 + lr) * 128 + ((kc * 4 + lg) ^ lr) * 8];
#pragma unroll
    for (int nf = 0; nf < 8; ++nf) {
      bf16x8 bf = *(const bf16x8*)
          &Bs[(nf * 16 + lr) * 128 + ((kc * 4 + lg) ^ lr) * 8];
      acc[0][nf] = __builtin_amdgcn_mfma_f32_16x16x32_bf16(a0, bf, acc[0][nf], 0, 0, 0);
      acc[1][nf] = __builtin_amdgcn_mfma_f32_16x16x32_bf16(a1, bf, acc[1][nf], 0, 0, 0);
    }
  }
#pragma unroll
  for (int fm = 0; fm < 2; ++fm)
#pragma unroll
    for (int nf = 0; nf < 8; ++nf)
#pragma unroll
      for (int r = 0; r < 4; ++r) {
        int row = ab + (w * 2 + fm) * 16 + lg * 4 + r;
        int col = bb + nf * 16 + lr;
        float v = acc[fm][nf][r] * INV_SQRT_D;
        L[(size_t)row * NCOL + col] = v;
        Eh[(size_t)row * EHP + col] = (_Float16)exp2f(v * LOG2E);
      }
}

__global__ void null_col_k(const float* __restrict__ Ap,
                           const float* __restrict__ nv, float* __restrict__ L,
                           _Float16* __restrict__ Eh) {
  int row = blockIdx.x, lane = threadIdx.x;
  float s = Ap[(size_t)row * HID_ + lane] * nv[lane] +
            Ap[(size_t)row * HID_ + 64 + lane] * nv[64 + lane];
  s = wred64(s);
  if (lane == 0) {
    float v = s * INV_SQRT_D;
    L[(size_t)row * NCOL + 4096] = v;
    Eh[(size_t)row * EHP + 4096] = (_Float16)exp2f(v * LOG2E);
  }
  if (lane >= 1 && lane < 8) Eh[(size_t)row * EHP + 4096 + lane] = (_Float16)0.f;
}

// ---------------- Sinkhorn: fused row pass + fp16 col partials --------------
// 512 blocks x 8 rows (r10 parallelism). Phase 1: u_i = 1/(E v) (vinv in LDS,
// conflict-free float4 ownership). Phase 2: per-block fp16 column partials
// (plain coalesced stores). Also zeroes t_new for the reduce that follows.
__global__ __launch_bounds__(256) void sink_fused_k(
    const _Float16* __restrict__ Eh, const float* __restrict__ t_old,
    float* __restrict__ t_new, _Float16* __restrict__ colpart,
    float* __restrict__ u, int first) {
  __shared__ float vinv[EHP];
  __shared__ float uls[8];
  const int tid = threadIdx.x, bid = blockIdx.x;
  if (tid < 9) {
    int z = bid * 9 + tid;
    if (z < EHP) t_new[z] = 0.f;
  }
  for (int i = tid; i < EHP; i += 256)
    vinv[i] = (i < NCOL) ? (first ? 1.f : 1.f / t_old[i]) : 0.f;
  __syncthreads();
  const int w = tid >> 6, l = tid & 63;
  const int row0 = bid * 8;
#pragma unroll
  for (int rr = 0; rr < 2; ++rr) {
    int row = row0 + w * 2 + rr;
    const _Float16* Ep = Eh + (size_t)row * EHP;
    float s = 0.f;
    for (int j = l * 4; j < EHP; j += 256) {
      half4v e = *(const half4v*)&Ep[j];
      float4 vv = *(const float4*)&vinv[j];
      s += (float)e[0] * vv.x + (float)e[1] * vv.y + (float)e[2] * vv.z +
           (float)e[3] * vv.w;
    }
    s = wred64(s);
    if (l == 0) {
      float uv = 1.f / s;
      uls[w * 2 + rr] = uv;
      u[row] = uv;
    }
  }
  __syncthreads();
  float ur[8];
#pragma unroll
  for (int r = 0; r < 8; ++r) ur[r] = uls[r];
  _Float16* cp = colpart + (size_t)bid * EHP;
  for (int j = tid * 4; j < EHP; j += 1024) {
    float a0 = 0.f, a1 = 0.f, a2 = 0.f, a3 = 0.f;
#pragma unroll
    for (int r = 0; r < 8; ++r) {
      half4v e = *(const half4v*)&Eh[(size_t)(row0 + r) * EHP + j];
      a0 += (float)e[0] * ur[r];
      a1 += (float)e[1] * ur[r];
      a2 += (float)e[2] * ur[r];
      a3 += (float)e[3] * ur[r];
    }
    half4v pk;
    pk[0] = (_Float16)a0; pk[1] = (_Float16)a1;
    pk[2] = (_Float16)a2; pk[3] = (_Float16)a3;
    *(half4v*)&cp[j] = pk;
  }
}

// reduce 512 fp16 partials -> t_new. grid (17, 8): 64 partials per block,
// one atomicAdd per col (8 contenders; t_new pre-zeroed by sink_fused_k).
__global__ __launch_bounds__(256) void sink_reduce_k(
    const _Float16* __restrict__ colpart, float* __restrict__ t_new) {
  int j = blockIdx.x * 256 + threadIdx.x;
  if (j >= EHP) return;
  int b0 = blockIdx.y * 64;
  float s = 0.f;
#pragma unroll 8
  for (int b = 0; b < 64; ++b)
    s += (float)colpart[(size_t)(b0 + b) * EHP + j];
  atomicAdd(&t_new[j], s);
}

// P = Eh * u_i * (1/t_j)
__global__ __launch_bounds__(256) void sink_finalE_k(
    const _Float16* __restrict__ Eh, const float* __restrict__ u,
    const float* __restrict__ t, float* __restrict__ P) {
  __shared__ float vls[NCOL];
  int tid = threadIdx.x, row = blockIdx.x;
  for (int i = tid; i < NCOL; i += 256) vls[i] = 1.f / t[i];
  __syncthreads();
  float ur = u[row];
  const _Float16* Ep = Eh + (size_t)row * EHP;
  float* Pp = P + (size_t)row * NCOL;
  for (int j = tid; j < NCOL; j += 256) Pp[j] = (float)Ep[j] * ur * vls[j];
}

// ---------------- host ------------------------------------------------------
extern "C" void kernel_launch(void* const* d_in, const int* in_sizes, int n_in,
                              void* d_out, int out_size, void* d_ws,
                              size_t ws_size, hipStream_t stream) {
  const float* A_x = (const float*)d_in[0];
  const int* A_ei = (const int*)d_in[1];
  const float* B_x = (const float*)d_in[2];
  const int* B_ei = (const int*)d_in[3];
  const float* in_w = (const float*)d_in[4];
  const float* in_b = (const float*)d_in[5];
  const float* gcn_w = (const float*)d_in[6];
  const float* gcn_b = (const float*)d_in[7];
  const float* lng = (const float*)d_in[8];
  const float* lnb = (const float*)d_in[9];
  const float* cq = (const float*)d_in[10];
  const float* ck = (const float*)d_in[11];
  const float* cv = (const float*)d_in[12];
  const float* co = (const float*)d_in[13];
  const float* cob = (const float*)d_in[14];
  const float* plg = (const float*)d_in[15];
  const float* plb = (const float*)d_in[16];
  const float* pw = (const float*)d_in[17];
  const float* pb = (const float*)d_in[18];
  const float* nullv = (const float*)d_in[19];
  const float* w1 = (const float*)d_in[20];
  const float* b1 = (const float*)d_in[21];
  const float* w2 = (const float*)d_in[22];
  const float* b2 = (const float*)d_in[23];

  float* ws = (float*)d_ws;
  size_t off = 0;
  auto alloc = [&](size_t n) { float* p = ws + off; off += n; return p; };
  const size_t NHE = (size_t)NN * HID_;
  // --- persistent zone (alive across sinkhorn) ---
  float* tA = alloc(NHE);
  float* tB = alloc(NHE);
  float* Ap = alloc(NHE);
  float* Bp = alloc(NHE);
  ushort* Apb = (ushort*)alloc(NHE / 2);
  ushort* Bpb = (ushort*)alloc(NHE / 2);
  float* uvec = alloc(NN);
  float* t0 = alloc(EHP);
  float* t1 = alloc(EHP);
  // --- overlay zone: encoder/attention buffers, later reused as Eh ---
  float* zone = ws + off;
  float* hA0 = alloc(NHE); float* hB0 = alloc(NHE);
  float* hA1 = alloc(NHE); float* hB1 = alloc(NHE);
  float* QA = alloc(NHE);  float* KAb = alloc(NHE); float* VAb = alloc(NHE);
  float* QB = alloc(NHE);  float* KBb = alloc(NHE); float* VBb = alloc(NHE);
  float* Opart = alloc(4 * NHE);
  float* lpart = alloc((size_t)16 * NN);
  float* dinvA = alloc(NN); float* dinvB = alloc(NN);
  int* ib = (int*)(ws + off);
  int* cntA = ib;             int* cntB = cntA + NN;
  int* fillA = cntB + NN;     int* fillB = fillA + NN;
  int* rpA = fillB + NN;      int* rpB = rpA + (NN + 1);
  int* srcA = rpB + (NN + 1); int* srcB = srcA + EE;
  size_t ints_floats = (size_t)(4 * NN + 2 * (NN + 1) + 2 * EE);
  // Eh overlays the zone; keep off past both the named buffers and Eh
  _Float16* Eh = (_Float16*)zone;
  {
    size_t named = (size_t)((ws + off) - zone) + ints_floats;
    size_t eh_floats = ((size_t)NN * EHP + 1) / 2;
    size_t need = eh_floats > named ? eh_floats : named;
    off = (size_t)(zone - ws) + need;
  }
  // fp16 colpart after the Eh overlay (512 x EHP halfs = 4.2 MB)
  _Float16* colpart = (_Float16*)alloc((size_t)512 * EHP / 2 + 8);

  float* Lout = (float*)d_out;
  float* Pout = Lout + (size_t)NN * NCOL;
  float* zA = Pout + (size_t)NN * NCOL;
  float* zB = zA + NHE;

  hipMemsetAsync(cntA, 0, 4 * NN * sizeof(int), stream);  // cnt + fill

  // input projection
  gemm128_k<true, false, false, false, false, false>
      <<<dim3(128, 2), 256, 0, stream>>>(A_x, B_x, nullptr, in_w, in_b,
                                         nullptr, nullptr, nullptr, nullptr,
                                         hA0, hB0, nullptr, nullptr);
  // CSR build
  count_deg_k<<<dim3(256, 2), 256, 0, stream>>>(A_ei, B_ei, cntA, cntB);
  scan_k<<<dim3(1, 2), 1024, 0, stream>>>(cntA, cntB, rpA, rpB, dinvA, dinvB);
  fill_k<<<dim3(256, 2), 256, 0, stream>>>(A_ei, B_ei, rpA, rpB, fillA, fillB,
                                           srcA, srcB);
  // GCN encode
  float* hA = hA0; float* hB = hB0; float* aA = hA1; float* aB = hB1;
  for (int l = 0; l < 2; ++l) {
    gemm128_k<false, false, false, false, false, false>
        <<<dim3(128, 2), 256, 0, stream>>>(
            hA, hB, nullptr, gcn_w + (size_t)l * HID_ * HID_, nullptr, nullptr,
            nullptr, nullptr, nullptr, tA, tB, nullptr, nullptr);
    gcn_agg_k<<<dim3(1024, 2), 256, 0, stream>>>(
        tA, tB, rpA, rpB, srcA, srcB, dinvA, dinvB, gcn_b + l * HID_,
        lng + l * HID_, lnb + l * HID_, hA, hB);
  }
  // cross attention layers (bf16 MFMA; combine fused into O-projection)
  for (int l = 0; l < 3; ++l) {
    const float* wq = cq + (size_t)l * HID_ * HID_;
    const float* wk = ck + (size_t)l * HID_ * HID_;
    const float* wv = cv + (size_t)l * HID_ * HID_;
    const float* wo = co + (size_t)l * HID_ * HID_;
    gemm_qkv_k<<<dim3(128, 2, 3), 256, 0, stream>>>(
        hA, hB, wq, wk, wv, (ushort*)QA, (ushort*)QB, (ushort*)KAb,
        (ushort*)KBb, (ushort*)VAb, (ushort*)VBb);
    attn_mfma_k<<<dim3(64, 4, 4), 256, 0, stream>>>(
        (ushort*)QA, (ushort*)KAb, (ushort*)VAb, (ushort*)QB, (ushort*)KBb,
        (ushort*)VBb, Opart, lpart);
    // O-projection with inline attention combine + bias + residual
    gemm128_k<true, false, true, false, false, true>
        <<<dim3(128, 2), 256, 0, stream>>>(Opart, nullptr, lpart, wo,
                                           cob + l * HID_, nullptr, nullptr,
                                           hA, hB, aA, aB, nullptr, nullptr);
    float* t;
    t = hA; hA = aA; aA = t;
    t = hB; hB = aB; aB = t;
  }
  // post-LN fused into projection (fp32 out + fused bf16 cast)
  gemm128_k<true, false, false, true, true, false>
      <<<dim3(128, 2), 256, 0, stream>>>(hA, hB, nullptr, pw, pb, plg, plb,
                                         nullptr, nullptr, Ap, Bp, Apb, Bpb);
  // logits + E = exp(L) (fp16), then null column
  gemm_nt_mfma_k<<<dim3(32, 32), 256, 0, stream>>>(Apb, Bpb, Lout, Eh);
  null_col_k<<<NN, 64, 0, stream>>>(Ap, nullv, Lout, Eh);
  // sinkhorn: fused row+colpart (fp16), contention-free reduce; ping-pong t
  float* tb[2] = {t0, t1};
  for (int it = 0; it < 20; ++it) {
    float* told = tb[it & 1];
    float* tnew = tb[(it + 1) & 1];
    sink_fused_k<<<512, 256, 0, stream>>>(Eh, told, tnew, colpart, uvec,
                                          it == 0 ? 1 : 0);
    sink_reduce_k<<<dim3(17, 8), 256, 0, stream>>>(colpart, tnew);
  }
  sink_finalE_k<<<NN, 256, 0, stream>>>(Eh, uvec, tb[0], Pout);
  // correspondence head
  gemm128_k<true, true, false, false, false, false>
      <<<dim3(128, 2), 256, 0, stream>>>(Ap, Bp, nullptr, w1, b1, nullptr,
                                         nullptr, nullptr, nullptr, tA, tB,
                                         nullptr, nullptr);
  gemm128_k<true, false, false, false, false, false>
      <<<dim3(128, 2), 256, 0, stream>>>(tA, tB, nullptr, w2, b2, nullptr,
                                         nullptr, nullptr, nullptr, zA, zB,
                                         nullptr, nullptr);
}

// Round 14
// 944.380 us; speedup vs baseline: 1.1754x; 1.0281x over previous
//
#include <hip/hip_runtime.h>
#include <hip/hip_bf16.h>
#include <math.h>

#define NN 4096
#define EE 65536
#define HID_ 128
#define HDIM 32
#define NCOL 4097
#define EHP 4104  // Eh padded row stride (halfs), 16B-aligned rows

static constexpr float SCALE_ATT = 0.17677669529663687f;   // 1/sqrt(32)
static constexpr float INV_SQRT_D = 0.08838834764831845f;  // 1/sqrt(128)
static constexpr float LOG2E = 1.4426950408889634f;

typedef __attribute__((ext_vector_type(8))) short bf16x8;
typedef __attribute__((ext_vector_type(4))) float f32x4;
typedef _Float16 half4v __attribute__((ext_vector_type(4)));

__device__ __forceinline__ float wred64(float v) {
#pragma unroll
  for (int m = 32; m > 0; m >>= 1) v += __shfl_xor(v, m, 64);
  return v;
}

__device__ __forceinline__ ushort f2b(float f) {
  __hip_bfloat16 h = __float2bfloat16(f);
  union { __hip_bfloat16 h; ushort u; } c;
  c.h = h;
  return c.u;
}

// round-half-up bf16 pack of two floats into one u32 (e0 low, e1 high)
__device__ __forceinline__ unsigned pack2bf(float e0, float e1) {
  return ((__float_as_uint(e1) + 0x8000u) & 0xffff0000u) |
         ((__float_as_uint(e0) + 0x8000u) >> 16);
}

// ---------------- generic [4096,128] @ [128,128] GEMM, pair-batched ---------
// N-split: blockIdx.z = 64-col half -> 2 blocks/CU (staging latency overlap).
// COMBINE: X = attention combine ((Opart[dir]+Opart[2+dir]) / lsum).
// LNORM: LayerNorm applied to the staged X tile in LDS (g=lng, b=lnb).
template <bool BIAS, bool RELU, bool RESID, bool BCAST, bool LNORM,
          bool COMBINE>
__global__ __launch_bounds__(256, 2) void gemm128_k(
    const float* __restrict__ x0, const float* __restrict__ x1,
    const float* __restrict__ lp, const float* __restrict__ w,
    const float* __restrict__ bias, const float* __restrict__ lng,
    const float* __restrict__ lnb, const float* __restrict__ res0,
    const float* __restrict__ res1, float* __restrict__ o0,
    float* __restrict__ o1, ushort* __restrict__ ob0,
    ushort* __restrict__ ob1) {
  const int dir = blockIdx.y;
  const int nh = blockIdx.z;  // 64-col half
  const float* x = dir ? x1 : x0;
  const float* res = dir ? res1 : res0;
  float* out = dir ? o1 : o0;
  ushort* outb = dir ? ob1 : ob0;
  __shared__ float Xs[32][132];
  __shared__ float Ws[32][64];
  const int tid = threadIdx.x;
  const int rowbase = blockIdx.x * 32;
#pragma unroll
  for (int i = 0; i < 4; ++i) {
    int lin = tid + i * 256;
    int r = lin >> 5, c4 = lin & 31;
    if (COMBINE) {
      int rowg = rowbase + r;
      int hh = c4 >> 3;  // head = (c4*4)/32
      float ls = lp[((size_t)(dir * 4 + hh)) * NN + rowg] +
                 lp[((size_t)((2 + dir) * 4 + hh)) * NN + rowg];
      float inv = 1.f / ls;
      float4 a =
          *(const float4*)&x0[((size_t)dir * NN + rowg) * HID_ + c4 * 4];
      float4 b =
          *(const float4*)&x0[((size_t)(2 + dir) * NN + rowg) * HID_ + c4 * 4];
      *(float4*)&Xs[r][c4 * 4] =
          make_float4((a.x + b.x) * inv, (a.y + b.y) * inv, (a.z + b.z) * inv,
                      (a.w + b.w) * inv);
    } else {
      *(float4*)&Xs[r][c4 * 4] =
          *(const float4*)&x[(size_t)(rowbase + r) * HID_ + c4 * 4];
    }
  }
  if (LNORM) {
    __syncthreads();
    int row = tid >> 3, sub = tid & 7;  // 32 rows x 8 threads (8 lanes/row)
    float vals[16];
    float s = 0.f;
#pragma unroll
    for (int i = 0; i < 16; ++i) {
      vals[i] = Xs[row][sub * 16 + i];
      s += vals[i];
    }
    s += __shfl_xor(s, 1, 64);
    s += __shfl_xor(s, 2, 64);
    s += __shfl_xor(s, 4, 64);
    float mean = s * (1.f / 128.f);
    float v2 = 0.f;
#pragma unroll
    for (int i = 0; i < 16; ++i) {
      float d = vals[i] - mean;
      vals[i] = d;
      v2 += d * d;
    }
    v2 += __shfl_xor(v2, 1, 64);
    v2 += __shfl_xor(v2, 2, 64);
    v2 += __shfl_xor(v2, 4, 64);
    float rs = rsqrtf(v2 * (1.f / 128.f) + 1e-5f);
#pragma unroll
    for (int i = 0; i < 16; ++i)
      Xs[row][sub * 16 + i] =
          vals[i] * rs * lng[sub * 16 + i] + lnb[sub * 16 + i];
  }
  float acc[2][4] = {};
  const int tr = tid >> 4, tc = tid & 15;
  const int r0 = tr * 2, c0 = tc * 4;
  for (int k0 = 0; k0 < 128; k0 += 32) {
    __syncthreads();
#pragma unroll
    for (int i = 0; i < 2; ++i) {
      int lin = tid + i * 256;
      int r = lin >> 4, c4 = lin & 15;
      *(float4*)&Ws[r][c4 * 4] =
          *(const float4*)&w[(size_t)(k0 + r) * HID_ + nh * 64 + c4 * 4];
    }
    __syncthreads();
#pragma unroll
    for (int kk = 0; kk < 32; kk += 4) {
      float4 wv0 = *(const float4*)&Ws[kk + 0][c0];
      float4 wv1 = *(const float4*)&Ws[kk + 1][c0];
      float4 wv2 = *(const float4*)&Ws[kk + 2][c0];
      float4 wv3 = *(const float4*)&Ws[kk + 3][c0];
#pragma unroll
      for (int r = 0; r < 2; ++r) {
        float4 xv = *(const float4*)&Xs[r0 + r][k0 + kk];
        acc[r][0] += xv.x * wv0.x + xv.y * wv1.x + xv.z * wv2.x + xv.w * wv3.x;
        acc[r][1] += xv.x * wv0.y + xv.y * wv1.y + xv.z * wv2.y + xv.w * wv3.y;
        acc[r][2] += xv.x * wv0.z + xv.y * wv1.z + xv.z * wv2.z + xv.w * wv3.z;
        acc[r][3] += xv.x * wv0.w + xv.y * wv1.w + xv.z * wv2.w + xv.w * wv3.w;
      }
    }
  }
  float4 bv = make_float4(0.f, 0.f, 0.f, 0.f);
  if (BIAS) bv = *(const float4*)&bias[nh * 64 + c0];
#pragma unroll
  for (int r = 0; r < 2; ++r) {
    size_t orow = (size_t)(rowbase + r0 + r) * HID_ + nh * 64 + c0;
    float4 ov;
    ov.x = acc[r][0] + bv.x;
    ov.y = acc[r][1] + bv.y;
    ov.z = acc[r][2] + bv.z;
    ov.w = acc[r][3] + bv.w;
    if (RESID) {
      float4 rv = *(const float4*)&res[orow];
      ov.x += rv.x; ov.y += rv.y; ov.z += rv.z; ov.w += rv.w;
    }
    if (RELU) {
      ov.x = fmaxf(ov.x, 0.f); ov.y = fmaxf(ov.y, 0.f);
      ov.z = fmaxf(ov.z, 0.f); ov.w = fmaxf(ov.w, 0.f);
    }
    *(float4*)&out[orow] = ov;
    if (BCAST) {
      *(ushort4*)&outb[orow] =
          make_ushort4(f2b(ov.x), f2b(ov.y), f2b(ov.z), f2b(ov.w));
    }
  }
}

// ---- fused Q/K/V projection, N-split: grid (128, 2, 6 = qkv*2+half) --------
__global__ __launch_bounds__(256, 2) void gemm_qkv_k(
    const float* __restrict__ x0, const float* __restrict__ x1,
    const float* __restrict__ wq, const float* __restrict__ wk,
    const float* __restrict__ wv, ushort* __restrict__ QA,
    ushort* __restrict__ QB, ushort* __restrict__ KA, ushort* __restrict__ KB,
    ushort* __restrict__ VA, ushort* __restrict__ VB) {
  const int z = blockIdx.z >> 1, nh = blockIdx.z & 1;
  const float* x = blockIdx.y ? x1 : x0;
  const float* w = (z == 0) ? wq : (z == 1 ? wk : wv);
  ushort* out = (z == 0) ? (blockIdx.y ? QB : QA)
                         : (z == 1 ? (blockIdx.y ? KB : KA)
                                   : (blockIdx.y ? VB : VA));
  const float scale = (z == 0) ? SCALE_ATT * LOG2E : 1.f;
  __shared__ float Xs[32][132];
  __shared__ float Ws[32][64];
  const int tid = threadIdx.x;
  const int rowbase = blockIdx.x * 32;
#pragma unroll
  for (int i = 0; i < 4; ++i) {
    int lin = tid + i * 256;
    int r = lin >> 5, c4 = lin & 31;
    *(float4*)&Xs[r][c4 * 4] =
        *(const float4*)&x[(size_t)(rowbase + r) * HID_ + c4 * 4];
  }
  float acc[2][4] = {};
  const int tr = tid >> 4, tc = tid & 15;
  const int r0 = tr * 2, c0 = tc * 4;
  for (int k0 = 0; k0 < 128; k0 += 32) {
    __syncthreads();
#pragma unroll
    for (int i = 0; i < 2; ++i) {
      int lin = tid + i * 256;
      int r = lin >> 4, c4 = lin & 15;
      *(float4*)&Ws[r][c4 * 4] =
          *(const float4*)&w[(size_t)(k0 + r) * HID_ + nh * 64 + c4 * 4];
    }
    __syncthreads();
#pragma unroll
    for (int kk = 0; kk < 32; kk += 4) {
      float4 wv0 = *(const float4*)&Ws[kk + 0][c0];
      float4 wv1 = *(const float4*)&Ws[kk + 1][c0];
      float4 wv2 = *(const float4*)&Ws[kk + 2][c0];
      float4 wv3 = *(const float4*)&Ws[kk + 3][c0];
#pragma unroll
      for (int r = 0; r < 2; ++r) {
        float4 xv = *(const float4*)&Xs[r0 + r][k0 + kk];
        acc[r][0] += xv.x * wv0.x + xv.y * wv1.x + xv.z * wv2.x + xv.w * wv3.x;
        acc[r][1] += xv.x * wv0.y + xv.y * wv1.y + xv.z * wv2.y + xv.w * wv3.y;
        acc[r][2] += xv.x * wv0.z + xv.y * wv1.z + xv.z * wv2.z + xv.w * wv3.z;
        acc[r][3] += xv.x * wv0.w + xv.y * wv1.w + xv.z * wv2.w + xv.w * wv3.w;
      }
    }
  }
  if (z < 2) {
#pragma unroll
    for (int r = 0; r < 2; ++r) {
      ushort4 pk = make_ushort4(
          f2b(acc[r][0] * scale), f2b(acc[r][1] * scale),
          f2b(acc[r][2] * scale), f2b(acc[r][3] * scale));
      *(ushort4*)&out[(size_t)(rowbase + r0 + r) * HID_ + nh * 64 + c0] = pk;
    }
  } else {
#pragma unroll
    for (int r = 0; r < 2; ++r)
#pragma unroll
      for (int c = 0; c < 4; ++c)
        out[(size_t)(nh * 64 + c0 + c) * NN + rowbase + r0 + r] =
            f2b(acc[r][c]);
  }
}

// ---------------- GCN graph build ------------------------------------------
__global__ void count_deg_k(const int* __restrict__ eiA,
                            const int* __restrict__ eiB, int* cntA, int* cntB) {
  int e = blockIdx.x * 256 + threadIdx.x;
  const int* ei = blockIdx.y ? eiB : eiA;
  int* cnt = blockIdx.y ? cntB : cntA;
  atomicAdd(&cnt[ei[EE + e]], 1);
}

__global__ __launch_bounds__(1024) void scan_k(const int* cntA, const int* cntB,
                                               int* rpA, int* rpB, float* dinvA,
                                               float* dinvB) {
  const int* cnt = blockIdx.y ? cntB : cntA;
  int* rp = blockIdx.y ? rpB : rpA;
  float* dinv = blockIdx.y ? dinvB : dinvA;
  __shared__ int part[1024];
  int tid = threadIdx.x;
  int v0 = cnt[tid * 4], v1 = cnt[tid * 4 + 1], v2 = cnt[tid * 4 + 2],
      v3 = cnt[tid * 4 + 3];
  int tot = v0 + v1 + v2 + v3;
  part[tid] = tot;
  __syncthreads();
  int x = tot;
  for (int off = 1; off < 1024; off <<= 1) {
    int y = (tid >= off) ? part[tid - off] : 0;
    __syncthreads();
    x += y;
    part[tid] = x;
    __syncthreads();
  }
  int excl = x - tot;
  rp[tid * 4] = excl;
  rp[tid * 4 + 1] = excl + v0;
  rp[tid * 4 + 2] = excl + v0 + v1;
  rp[tid * 4 + 3] = excl + v0 + v1 + v2;
  if (tid == 1023) rp[4096] = x;
  dinv[tid * 4] = rsqrtf((float)(v0 + 1));
  dinv[tid * 4 + 1] = rsqrtf((float)(v1 + 1));
  dinv[tid * 4 + 2] = rsqrtf((float)(v2 + 1));
  dinv[tid * 4 + 3] = rsqrtf((float)(v3 + 1));
}

__global__ void fill_k(const int* __restrict__ eiA, const int* __restrict__ eiB,
                       const int* rpA, const int* rpB, int* fillA, int* fillB,
                       int* srcA, int* srcB) {
  int e = blockIdx.x * 256 + threadIdx.x;
  const int* ei = blockIdx.y ? eiB : eiA;
  const int* rp = blockIdx.y ? rpB : rpA;
  int* fill = blockIdx.y ? fillB : fillA;
  int* src = blockIdx.y ? srcB : srcA;
  int d = ei[EE + e], s = ei[e];
  int pos = atomicAdd(&fill[d], 1);
  src[rp[d] + pos] = s;
}

// wave-per-node aggregation + bias + LayerNorm + ReLU
__global__ __launch_bounds__(256) void gcn_agg_k(
    const float* __restrict__ xlA, const float* __restrict__ xlB,
    const int* __restrict__ rpA, const int* __restrict__ rpB,
    const int* __restrict__ srcA, const int* __restrict__ srcB,
    const float* __restrict__ dinvA, const float* __restrict__ dinvB,
    const float* __restrict__ gb, const float* __restrict__ lg,
    const float* __restrict__ lb, float* __restrict__ outA,
    float* __restrict__ outB) {
  const float* xl = blockIdx.y ? xlB : xlA;
  const int* rp = blockIdx.y ? rpB : rpA;
  const int* src = blockIdx.y ? srcB : srcA;
  const float* dinv = blockIdx.y ? dinvB : dinvA;
  float* out = blockIdx.y ? outB : outA;
  int wid = threadIdx.x >> 6, lane = threadIdx.x & 63;
  int node = blockIdx.x * 4 + wid;
  int b = rp[node], e = rp[node + 1];
  float di = dinv[node];
  float a0 = 0.f, a1 = 0.f;
  for (int base = b; base < e; base += 64) {
    int rem = e - base;
    int sv = 0;
    float wv = 0.f;
    if (lane < rem) {
      int s = src[base + lane];
      sv = s;
      wv = dinv[s] * di;
    }
    int nch = rem < 64 ? rem : 64;
    for (int j = 0; j < nch; ++j) {
      int s = __shfl(sv, j, 64);
      float w = __shfl(wv, j, 64);
      a0 += xl[(size_t)s * HID_ + lane] * w;
      a1 += xl[(size_t)s * HID_ + 64 + lane] * w;
    }
  }
  a0 += xl[(size_t)node * HID_ + lane] * di * di;
  a1 += xl[(size_t)node * HID_ + 64 + lane] * di * di;
  a0 += gb[lane];
  a1 += gb[64 + lane];
  float mean = wred64(a0 + a1) * (1.f / 128.f);
  float d0 = a0 - mean, d1 = a1 - mean;
  float var = wred64(d0 * d0 + d1 * d1) * (1.f / 128.f);
  float rs = rsqrtf(var + 1e-5f);
  float o0 = d0 * rs * lg[lane] + lb[lane];
  float o1 = d1 * rs * lg[64 + lane] + lb[64 + lane];
  out[(size_t)node * HID_ + lane] = fmaxf(o0, 0.f);
  out[(size_t)node * HID_ + 64 + lane] = fmaxf(o1, 0.f);
}

// ---------------- MFMA attention, kv-split x2, double-buffered LDS ----------
__global__ __launch_bounds__(256, 4) void attn_mfma_k(
    const ushort* __restrict__ QA, const ushort* __restrict__ KA,
    const ushort* __restrict__ VtA, const ushort* __restrict__ QB,
    const ushort* __restrict__ KB, const ushort* __restrict__ VtB,
    float* __restrict__ Opart, float* __restrict__ lpart) {
  const int qt = blockIdx.x, h = blockIdx.y;
  const int dir = blockIdx.z >> 1, sl = blockIdx.z & 1;
  const ushort* Q = dir ? QB : QA;
  const ushort* K = dir ? KA : KB;
  const ushort* Vt = dir ? VtA : VtB;

  __shared__ ushort KF[2][2048];
  __shared__ ushort VF[2][2048];
  __shared__ ushort PF[4][1024];

  const int tid = threadIdx.x;
  const int w = tid >> 6, l = tid & 63;
  const int lr = l & 15, lg = l >> 4;

  const int qrow = qt * 64 + w * 16 + lr;
  bf16x8 qf = *(const bf16x8*)&Q[(size_t)qrow * HID_ + h * HDIM + lg * 8];

  f32x4 oacc0 = {0.f, 0.f, 0.f, 0.f};
  f32x4 oacc1 = {0.f, 0.f, 0.f, 0.f};
  float lsum = 0.f;

  const int ldst = ((w * 4 + lg) * 16 + lr) * 8;
  const ushort* Kg =
      K + (size_t)(sl * 2048 + w * 16 + lr) * HID_ + h * HDIM + lg * 8;
  const ushort* Vg = Vt + (size_t)(h * HDIM + (w >> 1) * 16 + lr) * NN +
                     sl * 2048 + (w & 1) * 32 + lg * 8;

  {
    bf16x8 k0 = *(const bf16x8*)Kg;
    bf16x8 v0 = *(const bf16x8*)Vg;
    *(bf16x8*)&KF[0][ldst] = k0;
    *(bf16x8*)&VF[0][ldst] = v0;
  }
  __syncthreads();

  for (int t = 0; t < 32; ++t) {
    const int cur = t & 1;
    bf16x8 kreg, vreg;
    if (t < 31) {
      kreg = *(const bf16x8*)&Kg[(size_t)(t + 1) * 64 * HID_];
      vreg = *(const bf16x8*)&Vg[(t + 1) * 64];
    }
#pragma unroll
    for (int s = 0; s < 4; ++s) {
      bf16x8 kf = *(const bf16x8*)&KF[cur][((s * 4 + lg) * 16 + lr) * 8];
      f32x4 c = {0.f, 0.f, 0.f, 0.f};
      c = __builtin_amdgcn_mfma_f32_16x16x32_bf16(kf, qf, c, 0, 0, 0);
      float e0 = exp2f(c[0]), e1 = exp2f(c[1]);
      float e2 = exp2f(c[2]), e3 = exp2f(c[3]);
      lsum += (e0 + e1) + (e2 + e3);
      const int k0 = s >> 1;
      const int lgr = (s & 1) * 2 + (lg >> 1);
      const int e8 = (lg & 1) * 4;
      *(uint2*)&PF[w][((k0 * 4 + lgr) * 16 + lr) * 8 + e8] =
          make_uint2(pack2bf(e0, e1), pack2bf(e2, e3));
    }
#pragma unroll
    for (int k0 = 0; k0 < 2; ++k0) {
      bf16x8 pa = *(const bf16x8*)&PF[w][((k0 * 4 + lg) * 16 + lr) * 8];
      bf16x8 vb0 = *(const bf16x8*)&VF[cur][((k0 * 4 + lg) * 16 + lr) * 8];
      bf16x8 vb1 =
          *(const bf16x8*)&VF[cur][(((2 + k0) * 4 + lg) * 16 + lr) * 8];
      oacc0 = __builtin_amdgcn_mfma_f32_16x16x32_bf16(pa, vb0, oacc0, 0, 0, 0);
      oacc1 = __builtin_amdgcn_mfma_f32_16x16x32_bf16(pa, vb1, oacc1, 0, 0, 0);
    }
    if (t < 31) {
      *(bf16x8*)&KF[cur ^ 1][ldst] = kreg;
      *(bf16x8*)&VF[cur ^ 1][ldst] = vreg;
    }
    __syncthreads();
  }
  lsum += __shfl_xor(lsum, 16, 64);
  lsum += __shfl_xor(lsum, 32, 64);
  const int pb = sl * 2 + dir;
  if (lg == 0)
    lpart[(size_t)(pb * 4 + h) * NN + qt * 64 + w * 16 + lr] = lsum;
#pragma unroll
  for (int r = 0; r < 4; ++r) {
    int q = qt * 64 + w * 16 + lg * 4 + r;
    Opart[((size_t)pb * NN + q) * HID_ + h * HDIM + lr] = oacc0[r];
    Opart[((size_t)pb * NN + q) * HID_ + h * HDIM + 16 + lr] = oacc1[r];
  }
}

// ---------------- logits via bf16 MFMA + fused Eh=exp(L) epilogue -----------
__global__ __launch_bounds__(256, 2) void gemm_nt_mfma_k(
    const ushort* __restrict__ Apb, const ushort* __restrict__ Bpb,
    float* __restrict__ L, _Float16* __restrict__ Eh) {
  __shared__ ushort As[128 * 128];
  __shared__ ushort Bs[128 * 128];
  const int tid = threadIdx.x;
  const int ab = blockIdx.y * 128, bb = blockIdx.x * 128;
#pragma unroll
  for (int i = 0; i < 8; ++i) {
    int lin = tid + i * 256;
    int row = lin >> 4, ch = lin & 15;
    int pch = ch ^ (row & 15);
    *(bf16x8*)&As[row * 128 + pch * 8] =
        *(const bf16x8*)&Apb[(size_t)(ab + row) * HID_ + ch * 8];
    *(bf16x8*)&Bs[row * 128 + pch * 8] =
        *(const bf16x8*)&Bpb[(size_t)(bb + row) * HID_ + ch * 8];
  }
  __syncthreads();
  const int w = tid >> 6, l = tid & 63, lr = l & 15, lg = l >> 4;
  f32x4 acc[2][8];
#pragma unroll
  for (int fm = 0; fm < 2; ++fm)
#pragma unroll
    for (int nf = 0; nf < 8; ++nf) acc[fm][nf] = {0.f, 0.f, 0.f, 0.f};
#pragma unroll
  for (int kc = 0; kc < 4; ++kc) {
    bf16x8 a0 = *(const bf16x8*)
        &As[((w * 2 + 0) * 16 + lr) * 128 + ((kc * 4 + lg) ^ lr) * 8];
    bf16x8 a1 = *(const bf16x8*)
        &As[((w * 2 + 1) * 16 + lr) * 128 + ((kc * 4 + lg) ^ lr) * 8];
#pragma unroll
    for (int nf = 0; nf < 8; ++nf) {
      bf16x8 bf = *(const bf16x8*)
          &Bs[(nf * 16 + lr) * 128 + ((kc * 4 + lg) ^ lr) * 8];
      acc[0][nf] = __builtin_amdgcn_mfma_f32_16x16x32_bf16(a0, bf, acc[0][nf], 0, 0, 0);
      acc[1][nf] = __builtin_amdgcn_mfma_f32_16x16x32_bf16(a1, bf, acc[1][nf], 0, 0, 0);
    }
  }
#pragma unroll
  for (int fm = 0; fm < 2; ++fm)
#pragma unroll
    for (int nf = 0; nf < 8; ++nf)
#pragma unroll
      for (int r = 0; r < 4; ++r) {
        int row = ab + (w * 2 + fm) * 16 + lg * 4 + r;
        int col = bb + nf * 16 + lr;
        float v = acc[fm][nf][r] * INV_SQRT_D;
        L[(size_t)row * NCOL + col] = v;
        Eh[(size_t)row * EHP + col] = (_Float16)exp2f(v * LOG2E);
      }
}

__global__ void null_col_k(const float* __restrict__ Ap,
                           const float* __restrict__ nv, float* __restrict__ L,
                           _Float16* __restrict__ Eh) {
  int row = blockIdx.x, lane = threadIdx.x;
  float s = Ap[(size_t)row * HID_ + lane] * nv[lane] +
            Ap[(size_t)row * HID_ + 64 + lane] * nv[64 + lane];
  s = wred64(s);
  if (lane == 0) {
    float v = s * INV_SQRT_D;
    L[(size_t)row * NCOL + 4096] = v;
    Eh[(size_t)row * EHP + 4096] = (_Float16)exp2f(v * LOG2E);
  }
  if (lane >= 1 && lane < 8) Eh[(size_t)row * EHP + 4096 + lane] = (_Float16)0.f;
}

// ---------------- Sinkhorn: fused row pass + fp16 col partials --------------
// 512 blocks x 8 rows. Phase 1: u_i = 1/(E v) (vinv in LDS, conflict-free
// float4 ownership). Phase 2: per-block fp16 column partials (plain stores).
__global__ __launch_bounds__(256) void sink_fused_k(
    const _Float16* __restrict__ Eh, const float* __restrict__ t_old,
    float* __restrict__ t_new, _Float16* __restrict__ colpart,
    float* __restrict__ u, int first) {
  __shared__ float vinv[EHP];
  __shared__ float uls[8];
  const int tid = threadIdx.x, bid = blockIdx.x;
  if (tid < 9) {
    int z = bid * 9 + tid;
    if (z < EHP) t_new[z] = 0.f;
  }
  for (int i = tid; i < EHP; i += 256)
    vinv[i] = (i < NCOL) ? (first ? 1.f : 1.f / t_old[i]) : 0.f;
  __syncthreads();
  const int w = tid >> 6, l = tid & 63;
  const int row0 = bid * 8;
#pragma unroll
  for (int rr = 0; rr < 2; ++rr) {
    int row = row0 + w * 2 + rr;
    const _Float16* Ep = Eh + (size_t)row * EHP;
    float s = 0.f;
    for (int j = l * 4; j < EHP; j += 256) {
      half4v e = *(const half4v*)&Ep[j];
      float4 vv = *(const float4*)&vinv[j];
      s += (float)e[0] * vv.x + (float)e[1] * vv.y + (float)e[2] * vv.z +
           (float)e[3] * vv.w;
    }
    s = wred64(s);
    if (l == 0) {
      float uv = 1.f / s;
      uls[w * 2 + rr] = uv;
      u[row] = uv;
    }
  }
  __syncthreads();
  float ur[8];
#pragma unroll
  for (int r = 0; r < 8; ++r) ur[r] = uls[r];
  _Float16* cp = colpart + (size_t)bid * EHP;
  for (int j = tid * 4; j < EHP; j += 1024) {
    float a0 = 0.f, a1 = 0.f, a2 = 0.f, a3 = 0.f;
#pragma unroll
    for (int r = 0; r < 8; ++r) {
      half4v e = *(const half4v*)&Eh[(size_t)(row0 + r) * EHP + j];
      a0 += (float)e[0] * ur[r];
      a1 += (float)e[1] * ur[r];
      a2 += (float)e[2] * ur[r];
      a3 += (float)e[3] * ur[r];
    }
    half4v pk;
    pk[0] = (_Float16)a0; pk[1] = (_Float16)a1;
    pk[2] = (_Float16)a2; pk[3] = (_Float16)a3;
    *(half4v*)&cp[j] = pk;
  }
}

// reduce 512 fp16 partials -> t_new. grid (17, 8): 64 partials per block,
// one atomicAdd per col (8 contenders; t_new pre-zeroed by sink_fused_k).
__global__ __launch_bounds__(256) void sink_reduce_k(
    const _Float16* __restrict__ colpart, float* __restrict__ t_new) {
  int j = blockIdx.x * 256 + threadIdx.x;
  if (j >= EHP) return;
  int b0 = blockIdx.y * 64;
  float s = 0.f;
#pragma unroll 8
  for (int b = 0; b < 64; ++b)
    s += (float)colpart[(size_t)(b0 + b) * EHP + j];
  atomicAdd(&t_new[j], s);
}

// P = Eh * u_i * (1/t_j)
__global__ __launch_bounds__(256) void sink_finalE_k(
    const _Float16* __restrict__ Eh, const float* __restrict__ u,
    const float* __restrict__ t, float* __restrict__ P) {
  __shared__ float vls[NCOL];
  int tid = threadIdx.x, row = blockIdx.x;
  for (int i = tid; i < NCOL; i += 256) vls[i] = 1.f / t[i];
  __syncthreads();
  float ur = u[row];
  const _Float16* Ep = Eh + (size_t)row * EHP;
  float* Pp = P + (size_t)row * NCOL;
  for (int j = tid; j < NCOL; j += 256) Pp[j] = (float)Ep[j] * ur * vls[j];
}

// ---------------- host ------------------------------------------------------
extern "C" void kernel_launch(void* const* d_in, const int* in_sizes, int n_in,
                              void* d_out, int out_size, void* d_ws,
                              size_t ws_size, hipStream_t stream) {
  const float* A_x = (const float*)d_in[0];
  const int* A_ei = (const int*)d_in[1];
  const float* B_x = (const float*)d_in[2];
  const int* B_ei = (const int*)d_in[3];
  const float* in_w = (const float*)d_in[4];
  const float* in_b = (const float*)d_in[5];
  const float* gcn_w = (const float*)d_in[6];
  const float* gcn_b = (const float*)d_in[7];
  const float* lng = (const float*)d_in[8];
  const float* lnb = (const float*)d_in[9];
  const float* cq = (const float*)d_in[10];
  const float* ck = (const float*)d_in[11];
  const float* cv = (const float*)d_in[12];
  const float* co = (const float*)d_in[13];
  const float* cob = (const float*)d_in[14];
  const float* plg = (const float*)d_in[15];
  const float* plb = (const float*)d_in[16];
  const float* pw = (const float*)d_in[17];
  const float* pb = (const float*)d_in[18];
  const float* nullv = (const float*)d_in[19];
  const float* w1 = (const float*)d_in[20];
  const float* b1 = (const float*)d_in[21];
  const float* w2 = (const float*)d_in[22];
  const float* b2 = (const float*)d_in[23];

  float* ws = (float*)d_ws;
  size_t off = 0;
  auto alloc = [&](size_t n) { float* p = ws + off; off += n; return p; };
  const size_t NHE = (size_t)NN * HID_;
  // --- persistent zone (alive across sinkhorn) ---
  float* tA = alloc(NHE);
  float* tB = alloc(NHE);
  float* Ap = alloc(NHE);
  float* Bp = alloc(NHE);
  ushort* Apb = (ushort*)alloc(NHE / 2);
  ushort* Bpb = (ushort*)alloc(NHE / 2);
  float* uvec = alloc(NN);
  float* t0 = alloc(EHP);
  float* t1 = alloc(EHP);
  // --- overlay zone: encoder/attention buffers, later reused as Eh ---
  float* zone = ws + off;
  float* hA0 = alloc(NHE); float* hB0 = alloc(NHE);
  float* hA1 = alloc(NHE); float* hB1 = alloc(NHE);
  float* QA = alloc(NHE);  float* KAb = alloc(NHE); float* VAb = alloc(NHE);
  float* QB = alloc(NHE);  float* KBb = alloc(NHE); float* VBb = alloc(NHE);
  float* Opart = alloc(4 * NHE);
  float* lpart = alloc((size_t)16 * NN);
  float* dinvA = alloc(NN); float* dinvB = alloc(NN);
  int* ib = (int*)(ws + off);
  int* cntA = ib;             int* cntB = cntA + NN;
  int* fillA = cntB + NN;     int* fillB = fillA + NN;
  int* rpA = fillB + NN;      int* rpB = rpA + (NN + 1);
  int* srcA = rpB + (NN + 1); int* srcB = srcA + EE;
  size_t ints_floats = (size_t)(4 * NN + 2 * (NN + 1) + 2 * EE);
  // Eh overlays the zone; keep off past both the named buffers and Eh
  _Float16* Eh = (_Float16*)zone;
  {
    size_t named = (size_t)((ws + off) - zone) + ints_floats;
    size_t eh_floats = ((size_t)NN * EHP + 1) / 2;
    size_t need = eh_floats > named ? eh_floats : named;
    off = (size_t)(zone - ws) + need;
  }
  // fp16 colpart after the Eh overlay (512 x EHP halfs = 4.2 MB)
  _Float16* colpart = (_Float16*)alloc((size_t)512 * EHP / 2 + 8);

  float* Lout = (float*)d_out;
  float* Pout = Lout + (size_t)NN * NCOL;
  float* zA = Pout + (size_t)NN * NCOL;
  float* zB = zA + NHE;

  hipMemsetAsync(cntA, 0, 4 * NN * sizeof(int), stream);  // cnt + fill

  // input projection
  gemm128_k<true, false, false, false, false, false>
      <<<dim3(128, 2, 2), 256, 0, stream>>>(A_x, B_x, nullptr, in_w, in_b,
                                            nullptr, nullptr, nullptr, nullptr,
                                            hA0, hB0, nullptr, nullptr);
  // CSR build
  count_deg_k<<<dim3(256, 2), 256, 0, stream>>>(A_ei, B_ei, cntA, cntB);
  scan_k<<<dim3(1, 2), 1024, 0, stream>>>(cntA, cntB, rpA, rpB, dinvA, dinvB);
  fill_k<<<dim3(256, 2), 256, 0, stream>>>(A_ei, B_ei, rpA, rpB, fillA, fillB,
                                           srcA, srcB);
  // GCN encode
  float* hA = hA0; float* hB = hB0; float* aA = hA1; float* aB = hB1;
  for (int l = 0; l < 2; ++l) {
    gemm128_k<false, false, false, false, false, false>
        <<<dim3(128, 2, 2), 256, 0, stream>>>(
            hA, hB, nullptr, gcn_w + (size_t)l * HID_ * HID_, nullptr, nullptr,
            nullptr, nullptr, nullptr, tA, tB, nullptr, nullptr);
    gcn_agg_k<<<dim3(1024, 2), 256, 0, stream>>>(
        tA, tB, rpA, rpB, srcA, srcB, dinvA, dinvB, gcn_b + l * HID_,
        lng + l * HID_, lnb + l * HID_, hA, hB);
  }
  // cross attention layers (bf16 MFMA; combine fused into O-projection)
  for (int l = 0; l < 3; ++l) {
    const float* wq = cq + (size_t)l * HID_ * HID_;
    const float* wk = ck + (size_t)l * HID_ * HID_;
    const float* wv = cv + (size_t)l * HID_ * HID_;
    const float* wo = co + (size_t)l * HID_ * HID_;
    gemm_qkv_k<<<dim3(128, 2, 6), 256, 0, stream>>>(
        hA, hB, wq, wk, wv, (ushort*)QA, (ushort*)QB, (ushort*)KAb,
        (ushort*)KBb, (ushort*)VAb, (ushort*)VBb);
    attn_mfma_k<<<dim3(64, 4, 4), 256, 0, stream>>>(
        (ushort*)QA, (ushort*)KAb, (ushort*)VAb, (ushort*)QB, (ushort*)KBb,
        (ushort*)VBb, Opart, lpart);
    // O-projection with inline attention combine + bias + residual
    gemm128_k<true, false, true, false, false, true>
        <<<dim3(128, 2, 2), 256, 0, stream>>>(Opart, nullptr, lpart, wo,
                                              cob + l * HID_, nullptr, nullptr,
                                              hA, hB, aA, aB, nullptr,
                                              nullptr);
    float* t;
    t = hA; hA = aA; aA = t;
    t = hB; hB = aB; aB = t;
  }
  // post-LN fused into projection (fp32 out + fused bf16 cast)
  gemm128_k<true, false, false, true, true, false>
      <<<dim3(128, 2, 2), 256, 0, stream>>>(hA, hB, nullptr, pw, pb, plg, plb,
                                            nullptr, nullptr, Ap, Bp, Apb,
                                            Bpb);
  // logits + E = exp(L) (fp16), then null column
  gemm_nt_mfma_k<<<dim3(32, 32), 256, 0, stream>>>(Apb, Bpb, Lout, Eh);
  null_col_k<<<NN, 64, 0, stream>>>(Ap, nullv, Lout, Eh);
  // sinkhorn: fused row+colpart (fp16), contention-free reduce; ping-pong t
  float* tb[2] = {t0, t1};
  for (int it = 0; it < 20; ++it) {
    float* told = tb[it & 1];
    float* tnew = tb[(it + 1) & 1];
    sink_fused_k<<<512, 256, 0, stream>>>(Eh, told, tnew, colpart, uvec,
                                          it == 0 ? 1 : 0);
    sink_reduce_k<<<dim3(17, 8), 256, 0, stream>>>(colpart, tnew);
  }
  sink_finalE_k<<<NN, 256, 0, stream>>>(Eh, uvec, tb[0], Pout);
  // correspondence head
  gemm128_k<true, true, false, false, false, false>
      <<<dim3(128, 2, 2), 256, 0, stream>>>(Ap, Bp, nullptr, w1, b1, nullptr,
                                            nullptr, nullptr, nullptr, tA, tB,
                                            nullptr, nullptr);
  gemm128_k<true, false, false, false, false, false>
      <<<dim3(128, 2, 2), 256, 0, stream>>>(tA, tB, nullptr, w2, b2, nullptr,
                                            nullptr, nullptr, nullptr, zA, zB,
                                            nullptr, nullptr);
}

// Round 15
// 943.898 us; speedup vs baseline: 1.1760x; 1.0005x over previous
//
#include <hip/hip_runtime.h>
#include <hip/hip_bf16.h>
#include <math.h>

#define NN 4096
#define EE 65536
#define HID_ 128
#define HDIM 32
#define NCOL 4097
#define EHP 4104  // Eh padded row stride (halfs), 16B-aligned rows

static constexpr float SCALE_ATT = 0.17677669529663687f;   // 1/sqrt(32)
static constexpr float INV_SQRT_D = 0.08838834764831845f;  // 1/sqrt(128)
static constexpr float LOG2E = 1.4426950408889634f;

typedef __attribute__((ext_vector_type(8))) short bf16x8;
typedef __attribute__((ext_vector_type(4))) float f32x4;
typedef _Float16 half4v __attribute__((ext_vector_type(4)));

__device__ __forceinline__ float wred64(float v) {
#pragma unroll
  for (int m = 32; m > 0; m >>= 1) v += __shfl_xor(v, m, 64);
  return v;
}

__device__ __forceinline__ ushort f2b(float f) {
  __hip_bfloat16 h = __float2bfloat16(f);
  union { __hip_bfloat16 h; ushort u; } c;
  c.h = h;
  return c.u;
}

// round-half-up bf16 pack of two floats into one u32 (e0 low, e1 high)
__device__ __forceinline__ unsigned pack2bf(float e0, float e1) {
  return ((__float_as_uint(e1) + 0x8000u) & 0xffff0000u) |
         ((__float_as_uint(e0) + 0x8000u) >> 16);
}

// ---------------- generic [4096,128] @ [128,128] GEMM, pair-batched ---------
// N-split: blockIdx.z = 64-col half -> 2 blocks/CU (staging latency overlap).
// COMBINE: X = attention combine (sum of 4 Opart kv-slices / lpart sums).
// LNORM: LayerNorm applied to the staged X tile in LDS (g=lng, b=lnb).
template <bool BIAS, bool RELU, bool RESID, bool BCAST, bool LNORM,
          bool COMBINE>
__global__ __launch_bounds__(256, 2) void gemm128_k(
    const float* __restrict__ x0, const float* __restrict__ x1,
    const float* __restrict__ lp, const float* __restrict__ w,
    const float* __restrict__ bias, const float* __restrict__ lng,
    const float* __restrict__ lnb, const float* __restrict__ res0,
    const float* __restrict__ res1, float* __restrict__ o0,
    float* __restrict__ o1, ushort* __restrict__ ob0,
    ushort* __restrict__ ob1) {
  const int dir = blockIdx.y;
  const int nh = blockIdx.z;  // 64-col half
  const float* x = dir ? x1 : x0;
  const float* res = dir ? res1 : res0;
  float* out = dir ? o1 : o0;
  ushort* outb = dir ? ob1 : ob0;
  __shared__ float Xs[32][132];
  __shared__ float Ws[32][64];
  const int tid = threadIdx.x;
  const int rowbase = blockIdx.x * 32;
#pragma unroll
  for (int i = 0; i < 4; ++i) {
    int lin = tid + i * 256;
    int r = lin >> 5, c4 = lin & 31;
    if (COMBINE) {
      int rowg = rowbase + r;
      int hh = c4 >> 3;  // head = (c4*4)/32
      float ls = 0.f;
#pragma unroll
      for (int sl = 0; sl < 4; ++sl)
        ls += lp[((size_t)((sl * 2 + dir) * 4 + hh)) * NN + rowg];
      float inv = 1.f / ls;
      float vx = 0.f, vy = 0.f, vz = 0.f, vw = 0.f;
#pragma unroll
      for (int sl = 0; sl < 4; ++sl) {
        float4 a = *(const float4*)&x0[((size_t)(sl * 2 + dir) * NN + rowg) *
                                           HID_ + c4 * 4];
        vx += a.x; vy += a.y; vz += a.z; vw += a.w;
      }
      *(float4*)&Xs[r][c4 * 4] =
          make_float4(vx * inv, vy * inv, vz * inv, vw * inv);
    } else {
      *(float4*)&Xs[r][c4 * 4] =
          *(const float4*)&x[(size_t)(rowbase + r) * HID_ + c4 * 4];
    }
  }
  if (LNORM) {
    __syncthreads();
    int row = tid >> 3, sub = tid & 7;  // 32 rows x 8 threads (8 lanes/row)
    float vals[16];
    float s = 0.f;
#pragma unroll
    for (int i = 0; i < 16; ++i) {
      vals[i] = Xs[row][sub * 16 + i];
      s += vals[i];
    }
    s += __shfl_xor(s, 1, 64);
    s += __shfl_xor(s, 2, 64);
    s += __shfl_xor(s, 4, 64);
    float mean = s * (1.f / 128.f);
    float v2 = 0.f;
#pragma unroll
    for (int i = 0; i < 16; ++i) {
      float d = vals[i] - mean;
      vals[i] = d;
      v2 += d * d;
    }
    v2 += __shfl_xor(v2, 1, 64);
    v2 += __shfl_xor(v2, 2, 64);
    v2 += __shfl_xor(v2, 4, 64);
    float rs = rsqrtf(v2 * (1.f / 128.f) + 1e-5f);
#pragma unroll
    for (int i = 0; i < 16; ++i)
      Xs[row][sub * 16 + i] =
          vals[i] * rs * lng[sub * 16 + i] + lnb[sub * 16 + i];
  }
  float acc[2][4] = {};
  const int tr = tid >> 4, tc = tid & 15;
  const int r0 = tr * 2, c0 = tc * 4;
  for (int k0 = 0; k0 < 128; k0 += 32) {
    __syncthreads();
#pragma unroll
    for (int i = 0; i < 2; ++i) {
      int lin = tid + i * 256;
      int r = lin >> 4, c4 = lin & 15;
      *(float4*)&Ws[r][c4 * 4] =
          *(const float4*)&w[(size_t)(k0 + r) * HID_ + nh * 64 + c4 * 4];
    }
    __syncthreads();
#pragma unroll
    for (int kk = 0; kk < 32; kk += 4) {
      float4 wv0 = *(const float4*)&Ws[kk + 0][c0];
      float4 wv1 = *(const float4*)&Ws[kk + 1][c0];
      float4 wv2 = *(const float4*)&Ws[kk + 2][c0];
      float4 wv3 = *(const float4*)&Ws[kk + 3][c0];
#pragma unroll
      for (int r = 0; r < 2; ++r) {
        float4 xv = *(const float4*)&Xs[r0 + r][k0 + kk];
        acc[r][0] += xv.x * wv0.x + xv.y * wv1.x + xv.z * wv2.x + xv.w * wv3.x;
        acc[r][1] += xv.x * wv0.y + xv.y * wv1.y + xv.z * wv2.y + xv.w * wv3.y;
        acc[r][2] += xv.x * wv0.z + xv.y * wv1.z + xv.z * wv2.z + xv.w * wv3.z;
        acc[r][3] += xv.x * wv0.w + xv.y * wv1.w + xv.z * wv2.w + xv.w * wv3.w;
      }
    }
  }
  float4 bv = make_float4(0.f, 0.f, 0.f, 0.f);
  if (BIAS) bv = *(const float4*)&bias[nh * 64 + c0];
#pragma unroll
  for (int r = 0; r < 2; ++r) {
    size_t orow = (size_t)(rowbase + r0 + r) * HID_ + nh * 64 + c0;
    float4 ov;
    ov.x = acc[r][0] + bv.x;
    ov.y = acc[r][1] + bv.y;
    ov.z = acc[r][2] + bv.z;
    ov.w = acc[r][3] + bv.w;
    if (RESID) {
      float4 rv = *(const float4*)&res[orow];
      ov.x += rv.x; ov.y += rv.y; ov.z += rv.z; ov.w += rv.w;
    }
    if (RELU) {
      ov.x = fmaxf(ov.x, 0.f); ov.y = fmaxf(ov.y, 0.f);
      ov.z = fmaxf(ov.z, 0.f); ov.w = fmaxf(ov.w, 0.f);
    }
    *(float4*)&out[orow] = ov;
    if (BCAST) {
      *(ushort4*)&outb[orow] =
          make_ushort4(f2b(ov.x), f2b(ov.y), f2b(ov.z), f2b(ov.w));
    }
  }
}

// ---- fused Q/K/V projection, N-split: grid (128, 2, 6 = qkv*2+half) --------
__global__ __launch_bounds__(256, 2) void gemm_qkv_k(
    const float* __restrict__ x0, const float* __restrict__ x1,
    const float* __restrict__ wq, const float* __restrict__ wk,
    const float* __restrict__ wv, ushort* __restrict__ QA,
    ushort* __restrict__ QB, ushort* __restrict__ KA, ushort* __restrict__ KB,
    ushort* __restrict__ VA, ushort* __restrict__ VB) {
  const int z = blockIdx.z >> 1, nh = blockIdx.z & 1;
  const float* x = blockIdx.y ? x1 : x0;
  const float* w = (z == 0) ? wq : (z == 1 ? wk : wv);
  ushort* out = (z == 0) ? (blockIdx.y ? QB : QA)
                         : (z == 1 ? (blockIdx.y ? KB : KA)
                                   : (blockIdx.y ? VB : VA));
  const float scale = (z == 0) ? SCALE_ATT * LOG2E : 1.f;
  __shared__ float Xs[32][132];
  __shared__ float Ws[32][64];
  const int tid = threadIdx.x;
  const int rowbase = blockIdx.x * 32;
#pragma unroll
  for (int i = 0; i < 4; ++i) {
    int lin = tid + i * 256;
    int r = lin >> 5, c4 = lin & 31;
    *(float4*)&Xs[r][c4 * 4] =
        *(const float4*)&x[(size_t)(rowbase + r) * HID_ + c4 * 4];
  }
  float acc[2][4] = {};
  const int tr = tid >> 4, tc = tid & 15;
  const int r0 = tr * 2, c0 = tc * 4;
  for (int k0 = 0; k0 < 128; k0 += 32) {
    __syncthreads();
#pragma unroll
    for (int i = 0; i < 2; ++i) {
      int lin = tid + i * 256;
      int r = lin >> 4, c4 = lin & 15;
      *(float4*)&Ws[r][c4 * 4] =
          *(const float4*)&w[(size_t)(k0 + r) * HID_ + nh * 64 + c4 * 4];
    }
    __syncthreads();
#pragma unroll
    for (int kk = 0; kk < 32; kk += 4) {
      float4 wv0 = *(const float4*)&Ws[kk + 0][c0];
      float4 wv1 = *(const float4*)&Ws[kk + 1][c0];
      float4 wv2 = *(const float4*)&Ws[kk + 2][c0];
      float4 wv3 = *(const float4*)&Ws[kk + 3][c0];
#pragma unroll
      for (int r = 0; r < 2; ++r) {
        float4 xv = *(const float4*)&Xs[r0 + r][k0 + kk];
        acc[r][0] += xv.x * wv0.x + xv.y * wv1.x + xv.z * wv2.x + xv.w * wv3.x;
        acc[r][1] += xv.x * wv0.y + xv.y * wv1.y + xv.z * wv2.y + xv.w * wv3.y;
        acc[r][2] += xv.x * wv0.z + xv.y * wv1.z + xv.z * wv2.z + xv.w * wv3.z;
        acc[r][3] += xv.x * wv0.w + xv.y * wv1.w + xv.z * wv2.w + xv.w * wv3.w;
      }
    }
  }
  if (z < 2) {
#pragma unroll
    for (int r = 0; r < 2; ++r) {
      ushort4 pk = make_ushort4(
          f2b(acc[r][0] * scale), f2b(acc[r][1] * scale),
          f2b(acc[r][2] * scale), f2b(acc[r][3] * scale));
      *(ushort4*)&out[(size_t)(rowbase + r0 + r) * HID_ + nh * 64 + c0] = pk;
    }
  } else {
#pragma unroll
    for (int r = 0; r < 2; ++r)
#pragma unroll
      for (int c = 0; c < 4; ++c)
        out[(size_t)(nh * 64 + c0 + c) * NN + rowbase + r0 + r] =
            f2b(acc[r][c]);
  }
}

// ---------------- GCN graph build ------------------------------------------
__global__ void count_deg_k(const int* __restrict__ eiA,
                            const int* __restrict__ eiB, int* cntA, int* cntB) {
  int e = blockIdx.x * 256 + threadIdx.x;
  const int* ei = blockIdx.y ? eiB : eiA;
  int* cnt = blockIdx.y ? cntB : cntA;
  atomicAdd(&cnt[ei[EE + e]], 1);
}

__global__ __launch_bounds__(1024) void scan_k(const int* cntA, const int* cntB,
                                               int* rpA, int* rpB, float* dinvA,
                                               float* dinvB) {
  const int* cnt = blockIdx.y ? cntB : cntA;
  int* rp = blockIdx.y ? rpB : rpA;
  float* dinv = blockIdx.y ? dinvB : dinvA;
  __shared__ int part[1024];
  int tid = threadIdx.x;
  int v0 = cnt[tid * 4], v1 = cnt[tid * 4 + 1], v2 = cnt[tid * 4 + 2],
      v3 = cnt[tid * 4 + 3];
  int tot = v0 + v1 + v2 + v3;
  part[tid] = tot;
  __syncthreads();
  int x = tot;
  for (int off = 1; off < 1024; off <<= 1) {
    int y = (tid >= off) ? part[tid - off] : 0;
    __syncthreads();
    x += y;
    part[tid] = x;
    __syncthreads();
  }
  int excl = x - tot;
  rp[tid * 4] = excl;
  rp[tid * 4 + 1] = excl + v0;
  rp[tid * 4 + 2] = excl + v0 + v1;
  rp[tid * 4 + 3] = excl + v0 + v1 + v2;
  if (tid == 1023) rp[4096] = x;
  dinv[tid * 4] = rsqrtf((float)(v0 + 1));
  dinv[tid * 4 + 1] = rsqrtf((float)(v1 + 1));
  dinv[tid * 4 + 2] = rsqrtf((float)(v2 + 1));
  dinv[tid * 4 + 3] = rsqrtf((float)(v3 + 1));
}

__global__ void fill_k(const int* __restrict__ eiA, const int* __restrict__ eiB,
                       const int* rpA, const int* rpB, int* fillA, int* fillB,
                       int* srcA, int* srcB) {
  int e = blockIdx.x * 256 + threadIdx.x;
  const int* ei = blockIdx.y ? eiB : eiA;
  const int* rp = blockIdx.y ? rpB : rpA;
  int* fill = blockIdx.y ? fillB : fillA;
  int* src = blockIdx.y ? srcB : srcA;
  int d = ei[EE + e], s = ei[e];
  int pos = atomicAdd(&fill[d], 1);
  src[rp[d] + pos] = s;
}

// wave-per-node aggregation + bias + LayerNorm + ReLU
__global__ __launch_bounds__(256) void gcn_agg_k(
    const float* __restrict__ xlA, const float* __restrict__ xlB,
    const int* __restrict__ rpA, const int* __restrict__ rpB,
    const int* __restrict__ srcA, const int* __restrict__ srcB,
    const float* __restrict__ dinvA, const float* __restrict__ dinvB,
    const float* __restrict__ gb, const float* __restrict__ lg,
    const float* __restrict__ lb, float* __restrict__ outA,
    float* __restrict__ outB) {
  const float* xl = blockIdx.y ? xlB : xlA;
  const int* rp = blockIdx.y ? rpB : rpA;
  const int* src = blockIdx.y ? srcB : srcA;
  const float* dinv = blockIdx.y ? dinvB : dinvA;
  float* out = blockIdx.y ? outB : outA;
  int wid = threadIdx.x >> 6, lane = threadIdx.x & 63;
  int node = blockIdx.x * 4 + wid;
  int b = rp[node], e = rp[node + 1];
  float di = dinv[node];
  float a0 = 0.f, a1 = 0.f;
  for (int base = b; base < e; base += 64) {
    int rem = e - base;
    int sv = 0;
    float wv = 0.f;
    if (lane < rem) {
      int s = src[base + lane];
      sv = s;
      wv = dinv[s] * di;
    }
    int nch = rem < 64 ? rem : 64;
    for (int j = 0; j < nch; ++j) {
      int s = __shfl(sv, j, 64);
      float w = __shfl(wv, j, 64);
      a0 += xl[(size_t)s * HID_ + lane] * w;
      a1 += xl[(size_t)s * HID_ + 64 + lane] * w;
    }
  }
  a0 += xl[(size_t)node * HID_ + lane] * di * di;
  a1 += xl[(size_t)node * HID_ + 64 + lane] * di * di;
  a0 += gb[lane];
  a1 += gb[64 + lane];
  float mean = wred64(a0 + a1) * (1.f / 128.f);
  float d0 = a0 - mean, d1 = a1 - mean;
  float var = wred64(d0 * d0 + d1 * d1) * (1.f / 128.f);
  float rs = rsqrtf(var + 1e-5f);
  float o0 = d0 * rs * lg[lane] + lb[lane];
  float o1 = d1 * rs * lg[64 + lane] + lb[64 + lane];
  out[(size_t)node * HID_ + lane] = fmaxf(o0, 0.f);
  out[(size_t)node * HID_ + 64 + lane] = fmaxf(o1, 0.f);
}

// ---------------- MFMA attention, kv-split x4, 8 blocks/CU ------------------
// grid (64 q-tiles, 4 heads, 8 = sl*2+dir), 256 threads (4 waves).
// Each block: 64 q-rows, kv range sl*1024..+1024 (16 tiles of 64).
// Double-buffered K/V LDS, one barrier per tile (r9 structure, r8 grid).
__global__ __launch_bounds__(256, 8) void attn_mfma_k(
    const ushort* __restrict__ QA, const ushort* __restrict__ KA,
    const ushort* __restrict__ VtA, const ushort* __restrict__ QB,
    const ushort* __restrict__ KB, const ushort* __restrict__ VtB,
    float* __restrict__ Opart, float* __restrict__ lpart) {
  const int qt = blockIdx.x, h = blockIdx.y;
  const int dir = blockIdx.z & 1, sl = blockIdx.z >> 1;
  const ushort* Q = dir ? QB : QA;
  const ushort* K = dir ? KA : KB;
  const ushort* Vt = dir ? VtA : VtB;

  __shared__ ushort KF[2][2048];
  __shared__ ushort VF[2][2048];
  __shared__ ushort PF[4][1024];

  const int tid = threadIdx.x;
  const int w = tid >> 6, l = tid & 63;
  const int lr = l & 15, lg = l >> 4;

  const int qrow = qt * 64 + w * 16 + lr;
  bf16x8 qf = *(const bf16x8*)&Q[(size_t)qrow * HID_ + h * HDIM + lg * 8];

  f32x4 oacc0 = {0.f, 0.f, 0.f, 0.f};
  f32x4 oacc1 = {0.f, 0.f, 0.f, 0.f};
  float lsum = 0.f;

  const int ldst = ((w * 4 + lg) * 16 + lr) * 8;
  const ushort* Kg =
      K + (size_t)(sl * 1024 + w * 16 + lr) * HID_ + h * HDIM + lg * 8;
  const ushort* Vg = Vt + (size_t)(h * HDIM + (w >> 1) * 16 + lr) * NN +
                     sl * 1024 + (w & 1) * 32 + lg * 8;

  {
    bf16x8 k0 = *(const bf16x8*)Kg;
    bf16x8 v0 = *(const bf16x8*)Vg;
    *(bf16x8*)&KF[0][ldst] = k0;
    *(bf16x8*)&VF[0][ldst] = v0;
  }
  __syncthreads();

  for (int t = 0; t < 16; ++t) {
    const int cur = t & 1;
    bf16x8 kreg, vreg;
    if (t < 15) {
      kreg = *(const bf16x8*)&Kg[(size_t)(t + 1) * 64 * HID_];
      vreg = *(const bf16x8*)&Vg[(t + 1) * 64];
    }
#pragma unroll
    for (int s = 0; s < 4; ++s) {
      bf16x8 kf = *(const bf16x8*)&KF[cur][((s * 4 + lg) * 16 + lr) * 8];
      f32x4 c = {0.f, 0.f, 0.f, 0.f};
      c = __builtin_amdgcn_mfma_f32_16x16x32_bf16(kf, qf, c, 0, 0, 0);
      float e0 = exp2f(c[0]), e1 = exp2f(c[1]);
      float e2 = exp2f(c[2]), e3 = exp2f(c[3]);
      lsum += (e0 + e1) + (e2 + e3);
      const int k0 = s >> 1;
      const int lgr = (s & 1) * 2 + (lg >> 1);
      const int e8 = (lg & 1) * 4;
      *(uint2*)&PF[w][((k0 * 4 + lgr) * 16 + lr) * 8 + e8] =
          make_uint2(pack2bf(e0, e1), pack2bf(e2, e3));
    }
#pragma unroll
    for (int k0 = 0; k0 < 2; ++k0) {
      bf16x8 pa = *(const bf16x8*)&PF[w][((k0 * 4 + lg) * 16 + lr) * 8];
      bf16x8 vb0 = *(const bf16x8*)&VF[cur][((k0 * 4 + lg) * 16 + lr) * 8];
      bf16x8 vb1 =
          *(const bf16x8*)&VF[cur][(((2 + k0) * 4 + lg) * 16 + lr) * 8];
      oacc0 = __builtin_amdgcn_mfma_f32_16x16x32_bf16(pa, vb0, oacc0, 0, 0, 0);
      oacc1 = __builtin_amdgcn_mfma_f32_16x16x32_bf16(pa, vb1, oacc1, 0, 0, 0);
    }
    if (t < 15) {
      *(bf16x8*)&KF[cur ^ 1][ldst] = kreg;
      *(bf16x8*)&VF[cur ^ 1][ldst] = vreg;
    }
    __syncthreads();
  }
  lsum += __shfl_xor(lsum, 16, 64);
  lsum += __shfl_xor(lsum, 32, 64);
  const int pb = sl * 2 + dir;
  if (lg == 0)
    lpart[(size_t)(pb * 4 + h) * NN + qt * 64 + w * 16 + lr] = lsum;
#pragma unroll
  for (int r = 0; r < 4; ++r) {
    int q = qt * 64 + w * 16 + lg * 4 + r;
    Opart[((size_t)pb * NN + q) * HID_ + h * HDIM + lr] = oacc0[r];
    Opart[((size_t)pb * NN + q) * HID_ + h * HDIM + 16 + lr] = oacc1[r];
  }
}

// ---------------- logits via bf16 MFMA + fused Eh=exp(L) epilogue -----------
__global__ __launch_bounds__(256, 2) void gemm_nt_mfma_k(
    const ushort* __restrict__ Apb, const ushort* __restrict__ Bpb,
    float* __restrict__ L, _Float16* __restrict__ Eh) {
  __shared__ ushort As[128 * 128];
  __shared__ ushort Bs[128 * 128];
  const int tid = threadIdx.x;
  const int ab = blockIdx.y * 128, bb = blockIdx.x * 128;
#pragma unroll
  for (int i = 0; i < 8; ++i) {
    int lin = tid + i * 256;
    int row = lin >> 4, ch = lin & 15;
    int pch = ch ^ (row & 15);
    *(bf16x8*)&As[row * 128 + pch * 8] =
        *(const bf16x8*)&Apb[(size_t)(ab + row) * HID_ + ch * 8];
    *(bf16x8*)&Bs[row * 128 + pch * 8] =
        *(const bf16x8*)&Bpb[(size_t)(bb + row) * HID_ + ch * 8];
  }
  __syncthreads();
  const int w = tid >> 6, l = tid & 63, lr = l & 15, lg = l >> 4;
  f32x4 acc[2][8];
#pragma unroll
  for (int fm = 0; fm < 2; ++fm)
#pragma unroll
    for (int nf = 0; nf < 8; ++nf) acc[fm][nf] = {0.f, 0.f, 0.f, 0.f};
#pragma unroll
  for (int kc = 0; kc < 4; ++kc) {
    bf16x8 a0 = *(const bf16x8*)
        &As[((w * 2 + 0) * 16 + lr) * 128 + ((kc * 4 + lg) ^ lr) * 8];
    bf16x8 a1 = *(const bf16x8*)
        &As[((w * 2 + 1) * 16 + lr) * 128 + ((kc * 4 + lg) ^ lr) * 8];
#pragma unroll
    for (int nf = 0; nf < 8; ++nf) {
      bf16x8 bf = *(const bf16x8*)
          &Bs[(nf * 16 + lr) * 128 + ((kc * 4 + lg) ^ lr) * 8];
      acc[0][nf] = __builtin_amdgcn_mfma_f32_16x16x32_bf16(a0, bf, acc[0][nf], 0, 0, 0);
      acc[1][nf] = __builtin_amdgcn_mfma_f32_16x16x32_bf16(a1, bf, acc[1][nf], 0, 0, 0);
    }
  }
#pragma unroll
  for (int fm = 0; fm < 2; ++fm)
#pragma unroll
    for (int nf = 0; nf < 8; ++nf)
#pragma unroll
      for (int r = 0; r < 4; ++r) {
        int row = ab + (w * 2 + fm) * 16 + lg * 4 + r;
        int col = bb + nf * 16 + lr;
        float v = acc[fm][nf][r] * INV_SQRT_D;
        L[(size_t)row * NCOL + col] = v;
        Eh[(size_t)row * EHP + col] = (_Float16)exp2f(v * LOG2E);
      }
}

__global__ void null_col_k(const float* __restrict__ Ap,
                           const float* __restrict__ nv, float* __restrict__ L,
                           _Float16* __restrict__ Eh) {
  int row = blockIdx.x, lane = threadIdx.x;
  float s = Ap[(size_t)row * HID_ + lane] * nv[lane] +
            Ap[(size_t)row * HID_ + 64 + lane] * nv[64 + lane];
  s = wred64(s);
  if (lane == 0) {
    float v = s * INV_SQRT_D;
    L[(size_t)row * NCOL + 4096] = v;
    Eh[(size_t)row * EHP + 4096] = (_Float16)exp2f(v * LOG2E);
  }
  if (lane >= 1 && lane < 8) Eh[(size_t)row * EHP + 4096 + lane] = (_Float16)0.f;
}

// ---------------- Sinkhorn: fused row pass + fp16 col partials --------------
// 512 blocks x 8 rows. Phase 1: u_i = 1/(E v) (vinv in LDS, conflict-free
// float4 ownership). Phase 2: per-block fp16 column partials (plain stores).
__global__ __launch_bounds__(256) void sink_fused_k(
    const _Float16* __restrict__ Eh, const float* __restrict__ t_old,
    float* __restrict__ t_new, _Float16* __restrict__ colpart,
    float* __restrict__ u, int first) {
  __shared__ float vinv[EHP];
  __shared__ float uls[8];
  const int tid = threadIdx.x, bid = blockIdx.x;
  if (tid < 9) {
    int z = bid * 9 + tid;
    if (z < EHP) t_new[z] = 0.f;
  }
  for (int i = tid; i < EHP; i += 256)
    vinv[i] = (i < NCOL) ? (first ? 1.f : 1.f / t_old[i]) : 0.f;
  __syncthreads();
  const int w = tid >> 6, l = tid & 63;
  const int row0 = bid * 8;
#pragma unroll
  for (int rr = 0; rr < 2; ++rr) {
    int row = row0 + w * 2 + rr;
    const _Float16* Ep = Eh + (size_t)row * EHP;
    float s = 0.f;
    for (int j = l * 4; j < EHP; j += 256) {
      half4v e = *(const half4v*)&Ep[j];
      float4 vv = *(const float4*)&vinv[j];
      s += (float)e[0] * vv.x + (float)e[1] * vv.y + (float)e[2] * vv.z +
           (float)e[3] * vv.w;
    }
    s = wred64(s);
    if (l == 0) {
      float uv = 1.f / s;
      uls[w * 2 + rr] = uv;
      u[row] = uv;
    }
  }
  __syncthreads();
  float ur[8];
#pragma unroll
  for (int r = 0; r < 8; ++r) ur[r] = uls[r];
  _Float16* cp = colpart + (size_t)bid * EHP;
  for (int j = tid * 4; j < EHP; j += 1024) {
    float a0 = 0.f, a1 = 0.f, a2 = 0.f, a3 = 0.f;
#pragma unroll
    for (int r = 0; r < 8; ++r) {
      half4v e = *(const half4v*)&Eh[(size_t)(row0 + r) * EHP + j];
      a0 += (float)e[0] * ur[r];
      a1 += (float)e[1] * ur[r];
      a2 += (float)e[2] * ur[r];
      a3 += (float)e[3] * ur[r];
    }
    half4v pk;
    pk[0] = (_Float16)a0; pk[1] = (_Float16)a1;
    pk[2] = (_Float16)a2; pk[3] = (_Float16)a3;
    *(half4v*)&cp[j] = pk;
  }
}

// reduce 512 fp16 partials -> t_new. grid (17, 8): 64 partials per block,
// one atomicAdd per col (8 contenders; t_new pre-zeroed by sink_fused_k).
__global__ __launch_bounds__(256) void sink_reduce_k(
    const _Float16* __restrict__ colpart, float* __restrict__ t_new) {
  int j = blockIdx.x * 256 + threadIdx.x;
  if (j >= EHP) return;
  int b0 = blockIdx.y * 64;
  float s = 0.f;
#pragma unroll 8
  for (int b = 0; b < 64; ++b)
    s += (float)colpart[(size_t)(b0 + b) * EHP + j];
  atomicAdd(&t_new[j], s);
}

// P = Eh * u_i * (1/t_j)
__global__ __launch_bounds__(256) void sink_finalE_k(
    const _Float16* __restrict__ Eh, const float* __restrict__ u,
    const float* __restrict__ t, float* __restrict__ P) {
  __shared__ float vls[NCOL];
  int tid = threadIdx.x, row = blockIdx.x;
  for (int i = tid; i < NCOL; i += 256) vls[i] = 1.f / t[i];
  __syncthreads();
  float ur = u[row];
  const _Float16* Ep = Eh + (size_t)row * EHP;
  float* Pp = P + (size_t)row * NCOL;
  for (int j = tid; j < NCOL; j += 256) Pp[j] = (float)Ep[j] * ur * vls[j];
}

// ---------------- host ------------------------------------------------------
extern "C" void kernel_launch(void* const* d_in, const int* in_sizes, int n_in,
                              void* d_out, int out_size, void* d_ws,
                              size_t ws_size, hipStream_t stream) {
  const float* A_x = (const float*)d_in[0];
  const int* A_ei = (const int*)d_in[1];
  const float* B_x = (const float*)d_in[2];
  const int* B_ei = (const int*)d_in[3];
  const float* in_w = (const float*)d_in[4];
  const float* in_b = (const float*)d_in[5];
  const float* gcn_w = (const float*)d_in[6];
  const float* gcn_b = (const float*)d_in[7];
  const float* lng = (const float*)d_in[8];
  const float* lnb = (const float*)d_in[9];
  const float* cq = (const float*)d_in[10];
  const float* ck = (const float*)d_in[11];
  const float* cv = (const float*)d_in[12];
  const float* co = (const float*)d_in[13];
  const float* cob = (const float*)d_in[14];
  const float* plg = (const float*)d_in[15];
  const float* plb = (const float*)d_in[16];
  const float* pw = (const float*)d_in[17];
  const float* pb = (const float*)d_in[18];
  const float* nullv = (const float*)d_in[19];
  const float* w1 = (const float*)d_in[20];
  const float* b1 = (const float*)d_in[21];
  const float* w2 = (const float*)d_in[22];
  const float* b2 = (const float*)d_in[23];

  float* ws = (float*)d_ws;
  size_t off = 0;
  auto alloc = [&](size_t n) { float* p = ws + off; off += n; return p; };
  const size_t NHE = (size_t)NN * HID_;
  // --- persistent zone (alive across sinkhorn) ---
  float* tA = alloc(NHE);
  float* tB = alloc(NHE);
  float* Ap = alloc(NHE);
  float* Bp = alloc(NHE);
  ushort* Apb = (ushort*)alloc(NHE / 2);
  ushort* Bpb = (ushort*)alloc(NHE / 2);
  float* uvec = alloc(NN);
  float* t0 = alloc(EHP);
  float* t1 = alloc(EHP);
  // --- overlay zone: encoder/attention buffers, later reused as Eh ---
  float* zone = ws + off;
  float* hA0 = alloc(NHE); float* hB0 = alloc(NHE);
  float* hA1 = alloc(NHE); float* hB1 = alloc(NHE);
  float* QA = alloc(NHE);  float* KAb = alloc(NHE); float* VAb = alloc(NHE);
  float* QB = alloc(NHE);  float* KBb = alloc(NHE); float* VBb = alloc(NHE);
  float* Opart = alloc(8 * NHE);
  float* lpart = alloc((size_t)32 * NN);
  float* dinvA = alloc(NN); float* dinvB = alloc(NN);
  int* ib = (int*)(ws + off);
  int* cntA = ib;             int* cntB = cntA + NN;
  int* fillA = cntB + NN;     int* fillB = fillA + NN;
  int* rpA = fillB + NN;      int* rpB = rpA + (NN + 1);
  int* srcA = rpB + (NN + 1); int* srcB = srcA + EE;
  size_t ints_floats = (size_t)(4 * NN + 2 * (NN + 1) + 2 * EE);
  // Eh overlays the zone; keep off past both the named buffers and Eh
  _Float16* Eh = (_Float16*)zone;
  {
    size_t named = (size_t)((ws + off) - zone) + ints_floats;
    size_t eh_floats = ((size_t)NN * EHP + 1) / 2;
    size_t need = eh_floats > named ? eh_floats : named;
    off = (size_t)(zone - ws) + need;
  }
  // fp16 colpart after the Eh overlay (512 x EHP halfs = 4.2 MB)
  _Float16* colpart = (_Float16*)alloc((size_t)512 * EHP / 2 + 8);

  float* Lout = (float*)d_out;
  float* Pout = Lout + (size_t)NN * NCOL;
  float* zA = Pout + (size_t)NN * NCOL;
  float* zB = zA + NHE;

  hipMemsetAsync(cntA, 0, 4 * NN * sizeof(int), stream);  // cnt + fill

  // input projection
  gemm128_k<true, false, false, false, false, false>
      <<<dim3(128, 2, 2), 256, 0, stream>>>(A_x, B_x, nullptr, in_w, in_b,
                                            nullptr, nullptr, nullptr, nullptr,
                                            hA0, hB0, nullptr, nullptr);
  // CSR build
  count_deg_k<<<dim3(256, 2), 256, 0, stream>>>(A_ei, B_ei, cntA, cntB);
  scan_k<<<dim3(1, 2), 1024, 0, stream>>>(cntA, cntB, rpA, rpB, dinvA, dinvB);
  fill_k<<<dim3(256, 2), 256, 0, stream>>>(A_ei, B_ei, rpA, rpB, fillA, fillB,
                                           srcA, srcB);
  // GCN encode
  float* hA = hA0; float* hB = hB0; float* aA = hA1; float* aB = hB1;
  for (int l = 0; l < 2; ++l) {
    gemm128_k<false, false, false, false, false, false>
        <<<dim3(128, 2, 2), 256, 0, stream>>>(
            hA, hB, nullptr, gcn_w + (size_t)l * HID_ * HID_, nullptr, nullptr,
            nullptr, nullptr, nullptr, tA, tB, nullptr, nullptr);
    gcn_agg_k<<<dim3(1024, 2), 256, 0, stream>>>(
        tA, tB, rpA, rpB, srcA, srcB, dinvA, dinvB, gcn_b + l * HID_,
        lng + l * HID_, lnb + l * HID_, hA, hB);
  }
  // cross attention layers (bf16 MFMA; combine fused into O-projection)
  for (int l = 0; l < 3; ++l) {
    const float* wq = cq + (size_t)l * HID_ * HID_;
    const float* wk = ck + (size_t)l * HID_ * HID_;
    const float* wv = cv + (size_t)l * HID_ * HID_;
    const float* wo = co + (size_t)l * HID_ * HID_;
    gemm_qkv_k<<<dim3(128, 2, 6), 256, 0, stream>>>(
        hA, hB, wq, wk, wv, (ushort*)QA, (ushort*)QB, (ushort*)KAb,
        (ushort*)KBb, (ushort*)VAb, (ushort*)VBb);
    attn_mfma_k<<<dim3(64, 4, 8), 256, 0, stream>>>(
        (ushort*)QA, (ushort*)KAb, (ushort*)VAb, (ushort*)QB, (ushort*)KBb,
        (ushort*)VBb, Opart, lpart);
    // O-projection with inline attention combine + bias + residual
    gemm128_k<true, false, true, false, false, true>
        <<<dim3(128, 2, 2), 256, 0, stream>>>(Opart, nullptr, lpart, wo,
                                              cob + l * HID_, nullptr, nullptr,
                                              hA, hB, aA, aB, nullptr,
                                              nullptr);
    float* t;
    t = hA; hA = aA; aA = t;
    t = hB; hB = aB; aB = t;
  }
  // post-LN fused into projection (fp32 out + fused bf16 cast)
  gemm128_k<true, false, false, true, true, false>
      <<<dim3(128, 2, 2), 256, 0, stream>>>(hA, hB, nullptr, pw, pb, plg, plb,
                                            nullptr, nullptr, Ap, Bp, Apb,
                                            Bpb);
  // logits + E = exp(L) (fp16), then null column
  gemm_nt_mfma_k<<<dim3(32, 32), 256, 0, stream>>>(Apb, Bpb, Lout, Eh);
  null_col_k<<<NN, 64, 0, stream>>>(Ap, nullv, Lout, Eh);
  // sinkhorn: fused row+colpart (fp16), contention-free reduce; ping-pong t
  float* tb[2] = {t0, t1};
  for (int it = 0; it < 20; ++it) {
    float* told = tb[it & 1];
    float* tnew = tb[(it + 1) & 1];
    sink_fused_k<<<512, 256, 0, stream>>>(Eh, told, tnew, colpart, uvec,
                                          it == 0 ? 1 : 0);
    sink_reduce_k<<<dim3(17, 8), 256, 0, stream>>>(colpart, tnew);
  }
  sink_finalE_k<<<NN, 256, 0, stream>>>(Eh, uvec, tb[0], Pout);
  // correspondence head
  gemm128_k<true, true, false, false, false, false>
      <<<dim3(128, 2, 2), 256, 0, stream>>>(Ap, Bp, nullptr, w1, b1, nullptr,
                                            nullptr, nullptr, nullptr, tA, tB,
                                            nullptr, nullptr);
  gemm128_k<true, false, false, false, false, false>
      <<<dim3(128, 2, 2), 256, 0, stream>>>(tA, tB, nullptr, w2, b2, nullptr,
                                            nullptr, nullptr, nullptr, zA, zB,
                                            nullptr, nullptr);
}